// Round 3
// baseline (1884.290 us; speedup 1.0000x reference)
//
#include <hip/hip_runtime.h>
#include <hip/hip_bf16.h>
#include <cstdint>
#include <cstddef>

#define Bb 16
#define Kk 2048
#define Pp 512
#define Ss 16
#define Cc 256
#define HEADOUT 325

typedef float v2f __attribute__((ext_vector_type(2)));

// ---------------- workspace layout (bytes) ----------------
static constexpr size_t OFF_TNORM = 0;                        // 10*512*4 = 20480
static constexpr size_t OFF_SUMS  = 20480;                    // 16384
static constexpr size_t OFF_INDS  = OFF_SUMS + 16384;         // 8192*4
static constexpr size_t OFF_IDXL  = OFF_INDS + 32768;         // 131072*4
static constexpr size_t OFF_GX    = OFF_IDXL + 524288;        // 131072*3*4
static constexpr size_t OFF_F1    = OFF_GX + 1572864;         // 32768*128*4
static constexpr size_t OFF_BIGA  = OFF_F1 + 16777216;        // 131072*128*4
static constexpr size_t OFF_BIGB  = OFF_BIGA + 67108864;      // 131072*128*4
static constexpr size_t OFF_FEAT  = OFF_BIGB + 67108864;      // 8192*128*4
static constexpr size_t OFF_C1    = OFF_FEAT + 4194304;
static constexpr size_t OFF_C2    = OFF_C1 + 4194304;
static constexpr size_t OFF_NET   = OFF_C2 + 4194304;         // 8192*325*4

// sum-slot float offsets inside OFF_SUMS
#define SB0S 0
#define SB0Q 128
#define SB1S 256
#define SB1Q 384
#define SB2S 512
#define SB2Q 640
#define SC1S 768
#define SC1Q 896
#define SC2S 1024
#define SC2Q 1152
#define SH0S 1280
#define SH0Q 1792
#define SH1S 2304
#define SH1Q 2816

// DPP-based f32 max with lane permute (no LDS path).
template <int CTRL>
__device__ __forceinline__ float fmax_dpp(float v) {
  int o = __builtin_amdgcn_update_dpp(0, __float_as_int(v), CTRL, 0xF, 0xF, true);
  return fmaxf(v, __int_as_float(o));
}

// ---------------- fused: fps (blocks 0..15) | F1 gemm (16..527) | tnorm (528)
__global__ __launch_bounds__(256, 1) void fused_pre(
    const float* __restrict__ xyz, int* __restrict__ inds,
    const float* __restrict__ features, const float* __restrict__ g_w0,
    float* __restrict__ F1, const float* __restrict__ text,
    float* __restrict__ tn) {
  __shared__ float smem[6400];  // union: fps 3*2048 | gemm 32*68 + 32*128
  const int tid = threadIdx.x;

  if (blockIdx.x < 16) {
    // ================= FPS: one wave per batch, register-resident =========
    #pragma clang fp contract(off)
    int b = blockIdx.x;
    float* px = smem;
    float* py = smem + 2048;
    float* pz = smem + 4096;
    const float* base = xyz + (size_t)b * Kk * 3;
    for (int i = tid; i < Kk; i += 256) {
      px[i] = base[3 * i]; py[i] = base[3 * i + 1]; pz[i] = base[3 * i + 2];
    }
    __syncthreads();
    if (tid >= 64) return;
    const int lane = tid;
    if (lane == 0) inds[b * Pp] = 0;
    // per-lane 32 points (lane-major: k = lane*32 + j), coords from GLOBAL so
    // the compiler cannot fold them back into (bank-conflicted) LDS reads.
    v2f PX[16], PY[16], PZ[16], DM[16];
    const float* pb = base + lane * 96;
    #pragma unroll
    for (int p = 0; p < 16; p++) {
      PX[p] = (v2f){pb[6 * p + 0], pb[6 * p + 3]};
      PY[p] = (v2f){pb[6 * p + 1], pb[6 * p + 4]};
      PZ[p] = (v2f){pb[6 * p + 2], pb[6 * p + 5]};
      DM[p] = (v2f){1e10f, 1e10f};
    }
    int last = 0;
    for (int it = 1; it < Pp; ++it) {
      float lx = px[last], ly = py[last], lz = pz[last];  // uniform bcast read
      v2f vlx = {lx, lx}, vly = {ly, ly}, vlz = {lz, lz};
      #pragma unroll
      for (int p = 0; p < 16; p++) {
        v2f dx = PX[p] - vlx, dy = PY[p] - vly, dz = PZ[p] - vlz;
        v2f d = (dx * dx + dy * dy) + dz * dz;
        DM[p] = __builtin_elementwise_min(DM[p], d);
      }
      // in-lane argmax tree (first-index tie-break; static indices)
      float bf[16]; int bk[16];
      #pragma unroll
      for (int p = 0; p < 16; p++) {
        bool t = DM[p].y > DM[p].x;
        bf[p] = t ? DM[p].y : DM[p].x;
        bk[p] = (p << 1) | (t ? 1 : 0);
      }
      #pragma unroll
      for (int s = 1; s < 16; s <<= 1) {
        #pragma unroll
        for (int p = 0; p < 16; p += (s << 1)) {
          bool t = bf[p + s] > bf[p];
          bf[p] = t ? bf[p + s] : bf[p];
          bk[p] = t ? bk[p + s] : bk[p];
        }
      }
      // cross-lane max: 4 DPP levels (xor1,2,7,15) + shfl for 16,32
      float g = bf[0];
      g = fmax_dpp<0xB1>(g);   // quad_perm [1,0,3,2]  = xor 1
      g = fmax_dpp<0x4E>(g);   // quad_perm [2,3,0,1]  = xor 2
      g = fmax_dpp<0x141>(g);  // row_half_mirror      = xor 7
      g = fmax_dpp<0x140>(g);  // row_mirror           = xor 15
      g = fmaxf(g, __shfl_xor(g, 16, 64));
      g = fmaxf(g, __shfl_xor(g, 32, 64));
      unsigned long long m = __ballot(bf[0] == g);
      int src = __builtin_ctzll(m);
      last = __shfl(lane * 32 + bk[0], src, 64);
      if (lane == 0) inds[b * Pp + it] = last;
    }
  } else if (blockIdx.x == 528) {
    // ================= text-feature normalization =========================
    int w = tid >> 6, lane = tid & 63;
    for (int r = w; r < 10; r += 4) {
      const float* rw = text + (size_t)r * 512;
      float v[8];
      float ss = 0.f;
      #pragma unroll
      for (int u = 0; u < 8; u++) { v[u] = rw[lane + 64 * u]; ss += v[u] * v[u]; }
      #pragma unroll
      for (int off = 32; off; off >>= 1) ss += __shfl_xor(ss, off, 64);
      float nrm = sqrtf(ss);
      #pragma unroll
      for (int u = 0; u < 8; u++)
        tn[(size_t)r * 512 + lane + 64 * u] = v[u] / nrm;
    }
  } else {
    // ================= F1 = feats_kc @ g_w0[3:,:]  (32768 x 256 x 128) ====
    float (*a_t)[68] = (float(*)[68])smem;
    float (*b_t)[128] = (float(*)[128])(smem + 32 * 68);
    const float* W = g_w0 + 3 * 128;
    const int m0 = (blockIdx.x - 16) * 64;
    float acc[4][8];
    #pragma unroll
    for (int i = 0; i < 4; i++)
      #pragma unroll
      for (int j = 0; j < 8; j++) acc[i][j] = 0.f;
    const int ty = tid >> 4, tx = tid & 15;
    const int lr = tid & 63, wv = tid >> 6;
    const int bb = m0 >> 11, k0 = m0 & 2047;
    const float* fb = features + (size_t)bb * (Cc * Kk);
    for (int c0 = 0; c0 < 256; c0 += 32) {
      #pragma unroll
      for (int i = 0; i < 8; i++) {
        int c = c0 + wv + 4 * i;
        a_t[wv + 4 * i][lr] = fb[(size_t)c * Kk + k0 + lr];
      }
      #pragma unroll
      for (int p = 0; p < 4; p++) {
        int cc = p * 8 + (tid >> 5);
        int nl = (tid & 31) * 4;
        *(float4*)&b_t[cc][nl] = *(const float4*)&W[(size_t)(c0 + cc) * 128 + nl];
      }
      __syncthreads();
      #pragma unroll
      for (int kk = 0; kk < 32; kk++) {
        float4 av = *(const float4*)&a_t[kk][ty * 4];
        float4 b0 = *(const float4*)&b_t[kk][tx * 4];
        float4 b1 = *(const float4*)&b_t[kk][tx * 4 + 64];
        float ap[4] = {av.x, av.y, av.z, av.w};
        float bq0[4] = {b0.x, b0.y, b0.z, b0.w};
        float bq1[4] = {b1.x, b1.y, b1.z, b1.w};
        #pragma unroll
        for (int i = 0; i < 4; i++) {
          #pragma unroll
          for (int u = 0; u < 4; u++) {
            acc[i][u] = fmaf(ap[i], bq0[u], acc[i][u]);
            acc[i][4 + u] = fmaf(ap[i], bq1[u], acc[i][4 + u]);
          }
        }
      }
      __syncthreads();
    }
    #pragma unroll
    for (int i = 0; i < 4; i++) {
      size_t mrow = (size_t)(m0 + ty * 4 + i);
      #pragma unroll
      for (int gq = 0; gq < 2; gq++) {
        float4 v4 = make_float4(acc[i][gq * 4], acc[i][gq * 4 + 1],
                                acc[i][gq * 4 + 2], acc[i][gq * 4 + 3]);
        *(float4*)&F1[mrow * 128 + gq * 64 + tx * 4] = v4;
      }
    }
  }
}

// ---------------- neighbor selection (first S ascending within radius) ------
__global__ __launch_bounds__(256) void neigh_k(const float* __restrict__ xyz,
                                               const int* __restrict__ inds,
                                               int* __restrict__ idxl,
                                               float* __restrict__ gx) {
  int widx = blockIdx.x * 4 + (threadIdx.x >> 6);
  int lane = threadIdx.x & 63;
  int b = widx >> 9;
  int q = inds[widx];
  const float* base = xyz + (size_t)b * Kk * 3;
  float qx = base[3 * q], qy = base[3 * q + 1], qz = base[3 * q + 2];
  int cnt = 0;
  int myk = 0;
  for (int ch = 0; ch < 32 && cnt < Ss; ch++) {
    int k = ch * 64 + lane;
    float dx = base[3 * k] - qx;
    float dy = base[3 * k + 1] - qy;
    float dz = base[3 * k + 2] - qz;
    float d2 = __fadd_rn(__fadd_rn(__fmul_rn(dx, dx), __fmul_rn(dy, dy)),
                         __fmul_rn(dz, dz));
    unsigned long long m = __ballot(d2 < 0.09f);
    while (m && cnt < Ss) {
      int t = __builtin_ctzll(m);
      if (lane == cnt) myk = ch * 64 + t;
      cnt++;
      m &= m - 1;
    }
  }
  int first = __shfl(myk, 0, 64);
  if (lane < Ss) {
    int kk = (lane < cnt) ? myk : first;
    size_t o = (size_t)widx * Ss + lane;
    idxl[o] = kk;
    gx[o * 3 + 0] = (base[3 * kk] - qx) / 0.3f;
    gx[o * 3 + 1] = (base[3 * kk + 1] - qy) / 0.3f;
    gx[o * 3 + 2] = (base[3 * kk + 2] - qz) / 0.3f;
  }
}

// ---------------- generic f32 GEMM: C = act_in(A) @ W (+bias), opt col-sums -
template <int KD, bool INBN, bool HASBIAS, bool OSUM>
__global__ __launch_bounds__(256) void gemm_f32(
    const float* __restrict__ A, int lda, const float* __restrict__ W, int N,
    const float* __restrict__ bias, const float* __restrict__ isum,
    const float* __restrict__ isq, float inv_cnt,
    const float* __restrict__ gamma, const float* __restrict__ beta,
    float* __restrict__ Cout, int ldc, float* __restrict__ osum,
    float* __restrict__ osq) {
  __shared__ float a_t[32][68];
  __shared__ float b_t[32][128];
  __shared__ float sc[INBN ? KD : 1];
  __shared__ float sh[INBN ? KD : 1];
  __shared__ float red_s[128];
  __shared__ float red_q[128];
  const int tid = threadIdx.x;
  const int m0 = blockIdx.x * 64;
  const int n0 = blockIdx.y * 128;
  if (INBN) {
    for (int c = tid; c < KD; c += 256) {
      float mean = isum[c] * inv_cnt;
      float var = isq[c] * inv_cnt - mean * mean;
      float is_ = rsqrtf(var + 1e-5f);
      float scl = gamma[c] * is_;
      sc[c] = scl;
      sh[c] = beta[c] - mean * scl;
    }
  }
  if (OSUM && tid < 128) { red_s[tid] = 0.f; red_q[tid] = 0.f; }
  __syncthreads();

  float acc[4][8];
  #pragma unroll
  for (int i = 0; i < 4; i++)
    #pragma unroll
    for (int j = 0; j < 8; j++) acc[i][j] = 0.f;

  const int ty = tid >> 4, tx = tid & 15;

  for (int c0 = 0; c0 < KD; c0 += 32) {
    {
      const int lr = tid >> 2, lcs = tid & 3;
      #pragma unroll
      for (int i = 0; i < 8; i++) {
        int c = c0 + lcs + 4 * i;
        float v = A[(size_t)(m0 + lr) * lda + c];
        if (INBN) v = fmaxf(fmaf(v, sc[c], sh[c]), 0.f);
        a_t[lcs + 4 * i][lr] = v;
      }
    }
    {
      #pragma unroll
      for (int p = 0; p < 4; p++) {
        int cc = p * 8 + (tid >> 5);
        int nl = (tid & 31) * 4;
        #pragma unroll
        for (int u = 0; u < 4; u++) {
          int n = n0 + nl + u;
          b_t[cc][nl + u] = (n < N) ? W[(size_t)(c0 + cc) * N + n] : 0.f;
        }
      }
    }
    __syncthreads();
    #pragma unroll
    for (int kk = 0; kk < 32; kk++) {
      float4 av = *(const float4*)&a_t[kk][ty * 4];
      float4 b0 = *(const float4*)&b_t[kk][tx * 4];
      float4 b1 = *(const float4*)&b_t[kk][tx * 4 + 64];
      float ap[4] = {av.x, av.y, av.z, av.w};
      float bq0[4] = {b0.x, b0.y, b0.z, b0.w};
      float bq1[4] = {b1.x, b1.y, b1.z, b1.w};
      #pragma unroll
      for (int i = 0; i < 4; i++) {
        #pragma unroll
        for (int u = 0; u < 4; u++) {
          acc[i][u] = fmaf(ap[i], bq0[u], acc[i][u]);
          acc[i][4 + u] = fmaf(ap[i], bq1[u], acc[i][4 + u]);
        }
      }
    }
    __syncthreads();
  }

  float ps[8], pq[8];
  #pragma unroll
  for (int j = 0; j < 8; j++) { ps[j] = 0.f; pq[j] = 0.f; }
  const bool full = (n0 + 128 <= N);
  #pragma unroll
  for (int i = 0; i < 4; i++) {
    size_t m = (size_t)(m0 + ty * 4 + i);
    #pragma unroll
    for (int g = 0; g < 2; g++) {
      float tmp[4];
      #pragma unroll
      for (int u = 0; u < 4; u++) {
        int j = g * 4 + u;
        int n = n0 + g * 64 + tx * 4 + u;
        float v = acc[i][j];
        if (HASBIAS && n < N) v += bias[n];
        tmp[u] = v;
        if (OSUM) { ps[j] += v; pq[j] += v * v; }
      }
      if (full) {
        float4 v4 = make_float4(tmp[0], tmp[1], tmp[2], tmp[3]);
        *(float4*)&Cout[m * ldc + n0 + g * 64 + tx * 4] = v4;
      } else {
        #pragma unroll
        for (int u = 0; u < 4; u++) {
          int n = n0 + g * 64 + tx * 4 + u;
          if (n < N) Cout[m * ldc + n] = tmp[u];
        }
      }
    }
  }
  if (OSUM) {
    #pragma unroll
    for (int g = 0; g < 2; g++)
      #pragma unroll
      for (int u = 0; u < 4; u++) {
        atomicAdd(&red_s[g * 64 + tx * 4 + u], ps[g * 4 + u]);
        atomicAdd(&red_q[g * 64 + tx * 4 + u], pq[g * 4 + u]);
      }
    __syncthreads();
    if (tid < 128) {
      atomicAdd(&osum[n0 + tid], red_s[tid]);
      atomicAdd(&osq[n0 + tid], red_q[tid]);
    }
  }
}

// ---------------- gather layer-1: L1 = F1[gather] + gx @ W0_xyz, + bn0 sums -
__global__ __launch_bounds__(256) void gather_l1(
    const float* __restrict__ F1, const int* __restrict__ idxl,
    const float* __restrict__ gx, const float* __restrict__ g_w0,
    float* __restrict__ L1, float* __restrict__ s0, float* __restrict__ q0) {
  int col = threadIdx.x & 127, half = threadIdx.x >> 7;
  int row0 = blockIdx.x * 64 + half * 32;
  float w0 = g_w0[col], w1 = g_w0[128 + col], w2 = g_w0[256 + col];
  __shared__ float rs[128], rq[128];
  if (threadIdx.x < 128) { rs[threadIdx.x] = 0.f; rq[threadIdx.x] = 0.f; }
  __syncthreads();
  float s = 0.f, q = 0.f;
  for (int rr = 0; rr < 32; rr++) {
    int row = row0 + rr;
    int b = row >> 13;
    int idx = idxl[row];
    float g0 = gx[(size_t)row * 3], g1 = gx[(size_t)row * 3 + 1],
          g2 = gx[(size_t)row * 3 + 2];
    float v = F1[((size_t)(b * Kk + idx)) * 128 + col] + g0 * w0 + g1 * w1 +
              g2 * w2;
    L1[(size_t)row * 128 + col] = v;
    s += v;
    q += v * v;
  }
  atomicAdd(&rs[col], s);
  atomicAdd(&rq[col], q);
  __syncthreads();
  if (threadIdx.x < 128) {
    atomicAdd(&s0[threadIdx.x], rs[threadIdx.x]);
    atomicAdd(&q0[threadIdx.x], rq[threadIdx.x]);
  }
}

// ---------------- bn + relu + max over S ----------------
__global__ __launch_bounds__(256) void maxpool_bn(
    const float* __restrict__ L3, const float* __restrict__ s2,
    const float* __restrict__ q2, const float* __restrict__ gam,
    const float* __restrict__ bet, float* __restrict__ feat) {
  int col = threadIdx.x & 127, half = threadIdx.x >> 7;
  int bq = blockIdx.x * 2 + half;
  float mean = s2[col] * (1.f / 131072.f);
  float var = q2[col] * (1.f / 131072.f) - mean * mean;
  float is_ = rsqrtf(var + 1e-5f);
  float scl = gam[col] * is_, shf = bet[col] - mean * scl;
  float m = -1e30f;
  #pragma unroll
  for (int s_ = 0; s_ < Ss; s_++) {
    float v = L3[((size_t)bq * Ss + s_) * 128 + col];
    v = fmaxf(fmaf(v, scl, shf), 0.f);
    m = fmaxf(m, v);
  }
  feat[(size_t)bq * 128 + col] = m;
}

// ---------------- final: q-norm, logits, coalesced transpose-assemble -------
__global__ __launch_bounds__(512) void final2(const float* __restrict__ net,
                                              const float* __restrict__ qbuf,
                                              const float* __restrict__ tn,
                                              float* __restrict__ out) {
  __shared__ float tile[79][65];
  const int blk = blockIdx.x;  // 128 blocks, 64 rows each
  const int tid = threadIdx.x;
  const int r = tid >> 3, oct = tid & 7;
  const int row = blk * 64 + r;
  const int b = (blk * 64) >> 9, p0 = (blk * 64) & 511;

  const float* qr = qbuf + (size_t)row * 512 + oct * 64;
  float4 q4[16];
  #pragma unroll
  for (int i = 0; i < 16; i++) q4[i] = *(const float4*)(qr + 4 * i);
  float ss = 0.f;
  float dot[10];
  #pragma unroll
  for (int t = 0; t < 10; t++) dot[t] = 0.f;
  #pragma unroll
  for (int i = 0; i < 16; i++) {
    float4 a = q4[i];
    ss += a.x * a.x + a.y * a.y + a.z * a.z + a.w * a.w;
    #pragma unroll
    for (int t = 0; t < 10; t++) {
      float4 b4 = *(const float4*)(tn + (size_t)t * 512 + oct * 64 + i * 4);
      dot[t] += a.x * b4.x + a.y * b4.y + a.z * b4.z + a.w * b4.w;
    }
  }
  #pragma unroll
  for (int off = 1; off < 8; off <<= 1) {
    ss += __shfl_xor(ss, off, 8);
    #pragma unroll
    for (int t = 0; t < 10; t++) dot[t] += __shfl_xor(dot[t], off, 8);
  }
  if (oct == 0) {
    float inv = rsqrtf(ss) * (1.f / 0.07f);
    #pragma unroll
    for (int t = 0; t < 10; t++) tile[69 + t][r] = dot[t] * inv;
  }
  // net channels 0..68 into tile
  for (int idx = tid; idx < 64 * 69; idx += 512) {
    int r2 = idx / 69, ch = idx - 69 * r2;
    tile[ch][r2] = net[(size_t)(blk * 64 + r2) * 325 + ch];
  }
  __syncthreads();
  // coalesced out write: out[b][ch][p0 + rr]
  for (int idx = tid; idx < 79 * 64; idx += 512) {
    int ch = idx >> 6, rr = idx & 63;
    out[((size_t)b * 79 + ch) * 512 + p0 + rr] = tile[ch][rr];
  }
}

extern "C" void kernel_launch(void* const* d_in, const int* in_sizes, int n_in,
                              void* d_out, int out_size, void* d_ws,
                              size_t ws_size, hipStream_t stream) {
  const float* xyz = (const float*)d_in[0];
  const float* features = (const float*)d_in[1];
  const float* text = (const float*)d_in[2];
  const float* g_w0 = (const float*)d_in[3];
  const float* g_w1 = (const float*)d_in[4];
  const float* g_w2 = (const float*)d_in[5];
  const float* g_gam0 = (const float*)d_in[6];
  const float* g_bet0 = (const float*)d_in[7];
  const float* g_gam1 = (const float*)d_in[8];
  const float* g_bet1 = (const float*)d_in[9];
  const float* g_gam2 = (const float*)d_in[10];
  const float* g_bet2 = (const float*)d_in[11];
  const float* conv1_w = (const float*)d_in[12];
  const float* conv1_b = (const float*)d_in[13];
  const float* bn1_g = (const float*)d_in[14];
  const float* bn1_b = (const float*)d_in[15];
  const float* conv2_w = (const float*)d_in[16];
  const float* conv2_b = (const float*)d_in[17];
  const float* bn2_g = (const float*)d_in[18];
  const float* bn2_b = (const float*)d_in[19];
  const float* conv3_w = (const float*)d_in[20];
  const float* conv3_b = (const float*)d_in[21];
  const float* h_w0 = (const float*)d_in[22];
  const float* h_b0 = (const float*)d_in[23];
  const float* h_g0 = (const float*)d_in[24];
  const float* h_be0 = (const float*)d_in[25];
  const float* h_w1 = (const float*)d_in[26];
  const float* h_b1 = (const float*)d_in[27];
  const float* h_g1 = (const float*)d_in[28];
  const float* h_be1 = (const float*)d_in[29];
  const float* h_w2 = (const float*)d_in[30];
  const float* h_b2 = (const float*)d_in[31];
  float* out = (float*)d_out;
  char* ws = (char*)d_ws;

  float* tn = (float*)(ws + OFF_TNORM);
  float* sums = (float*)(ws + OFF_SUMS);
  int* inds = (int*)(ws + OFF_INDS);
  int* idxl = (int*)(ws + OFF_IDXL);
  float* gx = (float*)(ws + OFF_GX);
  float* F1 = (float*)(ws + OFF_F1);
  float* BIGA = (float*)(ws + OFF_BIGA);
  float* BIGB = (float*)(ws + OFF_BIGB);
  float* feat = (float*)(ws + OFF_FEAT);
  float* c1 = (float*)(ws + OFF_C1);
  float* c2 = (float*)(ws + OFF_C2);
  float* net = (float*)(ws + OFF_NET);

  hipMemsetAsync(sums, 0, 16384, stream);
  // fps + F1 + tnorm fused (fps latency hides the F1 GEMM + tnorm)
  fused_pre<<<529, 256, 0, stream>>>(xyz, inds, features, g_w0, F1, text, tn);
  neigh_k<<<2048, 256, 0, stream>>>(xyz, inds, idxl, gx);
  gather_l1<<<2048, 256, 0, stream>>>(F1, idxl, gx, g_w0, BIGA, sums + SB0S,
                                      sums + SB0Q);
  gemm_f32<128, true, false, true><<<dim3(2048, 1), 256, 0, stream>>>(
      BIGA, 128, g_w1, 128, nullptr, sums + SB0S, sums + SB0Q, 1.f / 131072.f,
      g_gam0, g_bet0, BIGB, 128, sums + SB1S, sums + SB1Q);
  gemm_f32<128, true, false, true><<<dim3(2048, 1), 256, 0, stream>>>(
      BIGB, 128, g_w2, 128, nullptr, sums + SB1S, sums + SB1Q, 1.f / 131072.f,
      g_gam1, g_bet1, BIGA, 128, sums + SB2S, sums + SB2Q);
  maxpool_bn<<<4096, 256, 0, stream>>>(BIGA, sums + SB2S, sums + SB2Q, g_gam2,
                                       g_bet2, feat);
  gemm_f32<128, false, true, true><<<dim3(128, 1), 256, 0, stream>>>(
      feat, 128, conv1_w, 128, conv1_b, nullptr, nullptr, 0.f, nullptr,
      nullptr, c1, 128, sums + SC1S, sums + SC1Q);
  gemm_f32<128, true, true, true><<<dim3(128, 1), 256, 0, stream>>>(
      c1, 128, conv2_w, 128, conv2_b, sums + SC1S, sums + SC1Q, 1.f / 8192.f,
      bn1_g, bn1_b, c2, 128, sums + SC2S, sums + SC2Q);
  gemm_f32<128, true, true, false><<<dim3(128, 3), 256, 0, stream>>>(
      c2, 128, conv3_w, 325, conv3_b, sums + SC2S, sums + SC2Q, 1.f / 8192.f,
      bn2_g, bn2_b, net, 325, nullptr, nullptr);
  gemm_f32<256, false, true, true><<<dim3(128, 4), 256, 0, stream>>>(
      net + 69, 325, h_w0, 512, h_b0, nullptr, nullptr, 0.f, nullptr, nullptr,
      BIGB, 512, sums + SH0S, sums + SH0Q);
  gemm_f32<512, true, true, true><<<dim3(128, 4), 256, 0, stream>>>(
      BIGB, 512, h_w1, 512, h_b1, sums + SH0S, sums + SH0Q, 1.f / 8192.f, h_g0,
      h_be0, BIGA, 512, sums + SH1S, sums + SH1Q);
  gemm_f32<512, true, true, false><<<dim3(128, 4), 256, 0, stream>>>(
      BIGA, 512, h_w2, 512, h_b2, sums + SH1S, sums + SH1Q, 1.f / 8192.f, h_g1,
      h_be1, BIGB, 512, nullptr, nullptr);
  final2<<<128, 512, 0, stream>>>(net, BIGB, tn, out);
}

// Round 4
// 1168.569 us; speedup vs baseline: 1.6125x; 1.6125x over previous
//
#include <hip/hip_runtime.h>
#include <hip/hip_bf16.h>
#include <cstdint>
#include <cstddef>

#define Bb 16
#define Kk 2048
#define Pp 512
#define Ss 16
#define Cc 256
#define HEADOUT 325

// ---------------- workspace layout (bytes) ----------------
static constexpr size_t OFF_TNORM = 0;                        // 10*512*4 = 20480
static constexpr size_t OFF_SUMS  = 20480;                    // 16384
static constexpr size_t OFF_INDS  = OFF_SUMS + 16384;         // 8192*4
static constexpr size_t OFF_IDXL  = OFF_INDS + 32768;         // 131072*4
static constexpr size_t OFF_GX    = OFF_IDXL + 524288;        // 131072*3*4
static constexpr size_t OFF_F1    = OFF_GX + 1572864;         // 32768*128*4
static constexpr size_t OFF_BIGA  = OFF_F1 + 16777216;        // 131072*128*4
static constexpr size_t OFF_BIGB  = OFF_BIGA + 67108864;      // 131072*128*4
static constexpr size_t OFF_FEAT  = OFF_BIGB + 67108864;      // 8192*128*4
static constexpr size_t OFF_C1    = OFF_FEAT + 4194304;
static constexpr size_t OFF_C2    = OFF_C1 + 4194304;
static constexpr size_t OFF_NET   = OFF_C2 + 4194304;         // 8192*325*4

// sum-slot float offsets inside OFF_SUMS
#define SB0S 0
#define SB0Q 128
#define SB1S 256
#define SB1Q 384
#define SB2S 512
#define SB2Q 640
#define SC1S 768
#define SC1Q 896
#define SC2S 1024
#define SC2Q 1152
#define SH0S 1280
#define SH0Q 1792
#define SH1S 2304
#define SH1Q 2816

// DPP-based f32 max with lane permute (no LDS path).
template <int CTRL>
__device__ __forceinline__ float fmax_dpp(float v) {
  int o = __builtin_amdgcn_update_dpp(0, __float_as_int(v), CTRL, 0xF, 0xF, true);
  return fmaxf(v, __int_as_float(o));
}

// ---------------- fused: fps (blocks 0..15) | F1 gemm (16..527) | tnorm (528)
__global__ __launch_bounds__(256, 1) void fused_pre(
    const float* __restrict__ xyz, int* __restrict__ inds,
    const float* __restrict__ features, const float* __restrict__ g_w0,
    float* __restrict__ F1, const float* __restrict__ text,
    float* __restrict__ tn) {
  // union: fps pt4[2048] (8192 f) + redw (16 f)  |  gemm 32*68 + 32*128 = 6272 f
  __shared__ __align__(16) float smem[8208];
  const int tid = threadIdx.x;

  if (blockIdx.x < 16) {
    // ===== FPS: 4 waves, thread-major k = tid*8+j, ~32 floats/thread state ==
    #pragma clang fp contract(off)
    const int b = blockIdx.x;
    float4* pt4 = (float4*)smem;  // broadcast copy (uniform reads only)
    unsigned long long (*redw)[4] = (unsigned long long(*)[4])(smem + 8192);
    const float* base = xyz + (size_t)b * Kk * 3;
    for (int i = tid; i < Kk; i += 256) {
      pt4[i] = make_float4(base[3 * i], base[3 * i + 1], base[3 * i + 2], 0.f);
    }
    if (tid == 0) inds[b * Pp] = 0;
    // per-thread coords in registers (small arrays: no spill pressure)
    float cx[8], cy[8], cz[8], dm[8];
    {
      const float* pb = base + tid * 24;
      float4 f0 = *(const float4*)(pb + 0);
      float4 f1 = *(const float4*)(pb + 4);
      float4 f2 = *(const float4*)(pb + 8);
      float4 f3 = *(const float4*)(pb + 12);
      float4 f4 = *(const float4*)(pb + 16);
      float4 f5 = *(const float4*)(pb + 20);
      cx[0] = f0.x; cy[0] = f0.y; cz[0] = f0.z;
      cx[1] = f0.w; cy[1] = f1.x; cz[1] = f1.y;
      cx[2] = f1.z; cy[2] = f1.w; cz[2] = f2.x;
      cx[3] = f2.y; cy[3] = f2.z; cz[3] = f2.w;
      cx[4] = f3.x; cy[4] = f3.y; cz[4] = f3.z;
      cx[5] = f3.w; cy[5] = f4.x; cz[5] = f4.y;
      cx[6] = f4.z; cy[6] = f4.w; cz[6] = f5.x;
      cx[7] = f5.y; cy[7] = f5.z; cz[7] = f5.w;
      #pragma unroll
      for (int j = 0; j < 8; j++) dm[j] = 1e10f;
    }
    __syncthreads();
    const int lane = tid & 63, wid = tid >> 6;
    int last = 0;
    for (int it = 1; it < Pp; ++it) {
      float4 L = pt4[last];  // uniform-address broadcast, conflict-free
      float bf = -1.f;
      int bj = 0;
      #pragma unroll
      for (int j = 0; j < 8; j++) {
        float dx = cx[j] - L.x, dy = cy[j] - L.y, dz = cz[j] - L.z;
        float d = (dx * dx + dy * dy) + dz * dz;  // contract off: mul/add exact
        float m2 = fminf(dm[j], d);
        dm[j] = m2;
        if (m2 > bf) { bf = m2; bj = j; }  // strict >: first-j tie-break
      }
      // wave max (float): 4 DPP levels + 2 shfl
      float g = bf;
      g = fmax_dpp<0xB1>(g);   // xor 1
      g = fmax_dpp<0x4E>(g);   // xor 2
      g = fmax_dpp<0x141>(g);  // xor 7 (row_half_mirror)
      g = fmax_dpp<0x140>(g);  // xor 15 (row_mirror)
      g = fmaxf(g, __shfl_xor(g, 16, 64));
      g = fmaxf(g, __shfl_xor(g, 32, 64));
      // smallest lane with bf==g  ==  smallest k in wave (thread-major map)
      unsigned long long msk = __ballot(bf == g);
      int src = __builtin_ctzll(msk);
      int kk = (tid << 3) | bj;
      int kwin = __shfl(kk, src, 64);
      if (lane == 0)
        redw[it & 1][wid] = ((unsigned long long)__float_as_uint(g) << 32) |
                            (unsigned)(~(unsigned)kwin);
      __syncthreads();
      unsigned long long q0 = redw[it & 1][0], q1 = redw[it & 1][1];
      unsigned long long q2 = redw[it & 1][2], q3 = redw[it & 1][3];
      unsigned long long m0 = q0 > q1 ? q0 : q1;
      unsigned long long m1 = q2 > q3 ? q2 : q3;
      unsigned long long mm = m0 > m1 ? m0 : m1;
      last = (int)(~(unsigned)mm);  // low 32 bits hold ~k
      if (tid == 0) inds[b * Pp + it] = last;
      // no second barrier: redw is double-buffered on it&1
    }
  } else if (blockIdx.x == 528) {
    // ================= text-feature normalization =========================
    int w = tid >> 6, lane = tid & 63;
    for (int r = w; r < 10; r += 4) {
      const float* rw = text + (size_t)r * 512;
      float v[8];
      float ss = 0.f;
      #pragma unroll
      for (int u = 0; u < 8; u++) { v[u] = rw[lane + 64 * u]; ss += v[u] * v[u]; }
      #pragma unroll
      for (int off = 32; off; off >>= 1) ss += __shfl_xor(ss, off, 64);
      float nrm = sqrtf(ss);
      #pragma unroll
      for (int u = 0; u < 8; u++)
        tn[(size_t)r * 512 + lane + 64 * u] = v[u] / nrm;
    }
  } else {
    // ================= F1 = feats_kc @ g_w0[3:,:]  (32768 x 256 x 128) ====
    float (*a_t)[68] = (float(*)[68])smem;
    float (*b_t)[128] = (float(*)[128])(smem + 32 * 68);
    const float* W = g_w0 + 3 * 128;
    const int m0 = (blockIdx.x - 16) * 64;
    float acc[4][8];
    #pragma unroll
    for (int i = 0; i < 4; i++)
      #pragma unroll
      for (int j = 0; j < 8; j++) acc[i][j] = 0.f;
    const int ty = tid >> 4, tx = tid & 15;
    const int lr = tid & 63, wv = tid >> 6;
    const int bb = m0 >> 11, k0 = m0 & 2047;
    const float* fb = features + (size_t)bb * (Cc * Kk);
    for (int c0 = 0; c0 < 256; c0 += 32) {
      #pragma unroll
      for (int i = 0; i < 8; i++) {
        int c = c0 + wv + 4 * i;
        a_t[wv + 4 * i][lr] = fb[(size_t)c * Kk + k0 + lr];
      }
      #pragma unroll
      for (int p = 0; p < 4; p++) {
        int cc = p * 8 + (tid >> 5);
        int nl = (tid & 31) * 4;
        *(float4*)&b_t[cc][nl] = *(const float4*)&W[(size_t)(c0 + cc) * 128 + nl];
      }
      __syncthreads();
      #pragma unroll
      for (int kk = 0; kk < 32; kk++) {
        float4 av = *(const float4*)&a_t[kk][ty * 4];
        float4 b0 = *(const float4*)&b_t[kk][tx * 4];
        float4 b1 = *(const float4*)&b_t[kk][tx * 4 + 64];
        float ap[4] = {av.x, av.y, av.z, av.w};
        float bq0[4] = {b0.x, b0.y, b0.z, b0.w};
        float bq1[4] = {b1.x, b1.y, b1.z, b1.w};
        #pragma unroll
        for (int i = 0; i < 4; i++) {
          #pragma unroll
          for (int u = 0; u < 4; u++) {
            acc[i][u] = fmaf(ap[i], bq0[u], acc[i][u]);
            acc[i][4 + u] = fmaf(ap[i], bq1[u], acc[i][4 + u]);
          }
        }
      }
      __syncthreads();
    }
    #pragma unroll
    for (int i = 0; i < 4; i++) {
      size_t mrow = (size_t)(m0 + ty * 4 + i);
      #pragma unroll
      for (int gq = 0; gq < 2; gq++) {
        float4 v4 = make_float4(acc[i][gq * 4], acc[i][gq * 4 + 1],
                                acc[i][gq * 4 + 2], acc[i][gq * 4 + 3]);
        *(float4*)&F1[mrow * 128 + gq * 64 + tx * 4] = v4;
      }
    }
  }
}

// ---------------- neighbor selection (first S ascending within radius) ------
__global__ __launch_bounds__(256) void neigh_k(const float* __restrict__ xyz,
                                               const int* __restrict__ inds,
                                               int* __restrict__ idxl,
                                               float* __restrict__ gx) {
  int widx = blockIdx.x * 4 + (threadIdx.x >> 6);
  int lane = threadIdx.x & 63;
  int b = widx >> 9;
  int q = inds[widx];
  const float* base = xyz + (size_t)b * Kk * 3;
  float qx = base[3 * q], qy = base[3 * q + 1], qz = base[3 * q + 2];
  int cnt = 0;
  int myk = 0;
  for (int ch = 0; ch < 32 && cnt < Ss; ch++) {
    int k = ch * 64 + lane;
    float dx = base[3 * k] - qx;
    float dy = base[3 * k + 1] - qy;
    float dz = base[3 * k + 2] - qz;
    float d2 = __fadd_rn(__fadd_rn(__fmul_rn(dx, dx), __fmul_rn(dy, dy)),
                         __fmul_rn(dz, dz));
    unsigned long long m = __ballot(d2 < 0.09f);
    while (m && cnt < Ss) {
      int t = __builtin_ctzll(m);
      if (lane == cnt) myk = ch * 64 + t;
      cnt++;
      m &= m - 1;
    }
  }
  int first = __shfl(myk, 0, 64);
  if (lane < Ss) {
    int kk = (lane < cnt) ? myk : first;
    size_t o = (size_t)widx * Ss + lane;
    idxl[o] = kk;
    gx[o * 3 + 0] = (base[3 * kk] - qx) / 0.3f;
    gx[o * 3 + 1] = (base[3 * kk + 1] - qy) / 0.3f;
    gx[o * 3 + 2] = (base[3 * kk + 2] - qz) / 0.3f;
  }
}

// ---------------- generic f32 GEMM: C = act_in(A) @ W (+bias), opt col-sums -
template <int KD, bool INBN, bool HASBIAS, bool OSUM>
__global__ __launch_bounds__(256) void gemm_f32(
    const float* __restrict__ A, int lda, const float* __restrict__ W, int N,
    const float* __restrict__ bias, const float* __restrict__ isum,
    const float* __restrict__ isq, float inv_cnt,
    const float* __restrict__ gamma, const float* __restrict__ beta,
    float* __restrict__ Cout, int ldc, float* __restrict__ osum,
    float* __restrict__ osq) {
  __shared__ float a_t[32][68];
  __shared__ float b_t[32][128];
  __shared__ float sc[INBN ? KD : 1];
  __shared__ float sh[INBN ? KD : 1];
  __shared__ float red_s[128];
  __shared__ float red_q[128];
  const int tid = threadIdx.x;
  const int m0 = blockIdx.x * 64;
  const int n0 = blockIdx.y * 128;
  if (INBN) {
    for (int c = tid; c < KD; c += 256) {
      float mean = isum[c] * inv_cnt;
      float var = isq[c] * inv_cnt - mean * mean;
      float is_ = rsqrtf(var + 1e-5f);
      float scl = gamma[c] * is_;
      sc[c] = scl;
      sh[c] = beta[c] - mean * scl;
    }
  }
  if (OSUM && tid < 128) { red_s[tid] = 0.f; red_q[tid] = 0.f; }
  __syncthreads();

  float acc[4][8];
  #pragma unroll
  for (int i = 0; i < 4; i++)
    #pragma unroll
    for (int j = 0; j < 8; j++) acc[i][j] = 0.f;

  const int ty = tid >> 4, tx = tid & 15;

  for (int c0 = 0; c0 < KD; c0 += 32) {
    {
      const int lr = tid >> 2, lcs = tid & 3;
      #pragma unroll
      for (int i = 0; i < 8; i++) {
        int c = c0 + lcs + 4 * i;
        float v = A[(size_t)(m0 + lr) * lda + c];
        if (INBN) v = fmaxf(fmaf(v, sc[c], sh[c]), 0.f);
        a_t[lcs + 4 * i][lr] = v;
      }
    }
    {
      #pragma unroll
      for (int p = 0; p < 4; p++) {
        int cc = p * 8 + (tid >> 5);
        int nl = (tid & 31) * 4;
        #pragma unroll
        for (int u = 0; u < 4; u++) {
          int n = n0 + nl + u;
          b_t[cc][nl + u] = (n < N) ? W[(size_t)(c0 + cc) * N + n] : 0.f;
        }
      }
    }
    __syncthreads();
    #pragma unroll
    for (int kk = 0; kk < 32; kk++) {
      float4 av = *(const float4*)&a_t[kk][ty * 4];
      float4 b0 = *(const float4*)&b_t[kk][tx * 4];
      float4 b1 = *(const float4*)&b_t[kk][tx * 4 + 64];
      float ap[4] = {av.x, av.y, av.z, av.w};
      float bq0[4] = {b0.x, b0.y, b0.z, b0.w};
      float bq1[4] = {b1.x, b1.y, b1.z, b1.w};
      #pragma unroll
      for (int i = 0; i < 4; i++) {
        #pragma unroll
        for (int u = 0; u < 4; u++) {
          acc[i][u] = fmaf(ap[i], bq0[u], acc[i][u]);
          acc[i][4 + u] = fmaf(ap[i], bq1[u], acc[i][4 + u]);
        }
      }
    }
    __syncthreads();
  }

  float ps[8], pq[8];
  #pragma unroll
  for (int j = 0; j < 8; j++) { ps[j] = 0.f; pq[j] = 0.f; }
  const bool full = (n0 + 128 <= N);
  #pragma unroll
  for (int i = 0; i < 4; i++) {
    size_t m = (size_t)(m0 + ty * 4 + i);
    #pragma unroll
    for (int g = 0; g < 2; g++) {
      float tmp[4];
      #pragma unroll
      for (int u = 0; u < 4; u++) {
        int j = g * 4 + u;
        int n = n0 + g * 64 + tx * 4 + u;
        float v = acc[i][j];
        if (HASBIAS && n < N) v += bias[n];
        tmp[u] = v;
        if (OSUM) { ps[j] += v; pq[j] += v * v; }
      }
      if (full) {
        float4 v4 = make_float4(tmp[0], tmp[1], tmp[2], tmp[3]);
        *(float4*)&Cout[m * ldc + n0 + g * 64 + tx * 4] = v4;
      } else {
        #pragma unroll
        for (int u = 0; u < 4; u++) {
          int n = n0 + g * 64 + tx * 4 + u;
          if (n < N) Cout[m * ldc + n] = tmp[u];
        }
      }
    }
  }
  if (OSUM) {
    #pragma unroll
    for (int g = 0; g < 2; g++)
      #pragma unroll
      for (int u = 0; u < 4; u++) {
        atomicAdd(&red_s[g * 64 + tx * 4 + u], ps[g * 4 + u]);
        atomicAdd(&red_q[g * 64 + tx * 4 + u], pq[g * 4 + u]);
      }
    __syncthreads();
    if (tid < 128) {
      atomicAdd(&osum[n0 + tid], red_s[tid]);
      atomicAdd(&osq[n0 + tid], red_q[tid]);
    }
  }
}

// ---------------- gather layer-1: L1 = F1[gather] + gx @ W0_xyz, + bn0 sums -
__global__ __launch_bounds__(256) void gather_l1(
    const float* __restrict__ F1, const int* __restrict__ idxl,
    const float* __restrict__ gx, const float* __restrict__ g_w0,
    float* __restrict__ L1, float* __restrict__ s0, float* __restrict__ q0) {
  int col = threadIdx.x & 127, half = threadIdx.x >> 7;
  int row0 = blockIdx.x * 64 + half * 32;
  float w0 = g_w0[col], w1 = g_w0[128 + col], w2 = g_w0[256 + col];
  __shared__ float rs[128], rq[128];
  if (threadIdx.x < 128) { rs[threadIdx.x] = 0.f; rq[threadIdx.x] = 0.f; }
  __syncthreads();
  float s = 0.f, q = 0.f;
  for (int rr = 0; rr < 32; rr++) {
    int row = row0 + rr;
    int b = row >> 13;
    int idx = idxl[row];
    float g0 = gx[(size_t)row * 3], g1 = gx[(size_t)row * 3 + 1],
          g2 = gx[(size_t)row * 3 + 2];
    float v = F1[((size_t)(b * Kk + idx)) * 128 + col] + g0 * w0 + g1 * w1 +
              g2 * w2;
    L1[(size_t)row * 128 + col] = v;
    s += v;
    q += v * v;
  }
  atomicAdd(&rs[col], s);
  atomicAdd(&rq[col], q);
  __syncthreads();
  if (threadIdx.x < 128) {
    atomicAdd(&s0[threadIdx.x], rs[threadIdx.x]);
    atomicAdd(&q0[threadIdx.x], rq[threadIdx.x]);
  }
}

// ---------------- bn + relu + max over S ----------------
__global__ __launch_bounds__(256) void maxpool_bn(
    const float* __restrict__ L3, const float* __restrict__ s2,
    const float* __restrict__ q2, const float* __restrict__ gam,
    const float* __restrict__ bet, float* __restrict__ feat) {
  int col = threadIdx.x & 127, half = threadIdx.x >> 7;
  int bq = blockIdx.x * 2 + half;
  float mean = s2[col] * (1.f / 131072.f);
  float var = q2[col] * (1.f / 131072.f) - mean * mean;
  float is_ = rsqrtf(var + 1e-5f);
  float scl = gam[col] * is_, shf = bet[col] - mean * scl;
  float m = -1e30f;
  #pragma unroll
  for (int s_ = 0; s_ < Ss; s_++) {
    float v = L3[((size_t)bq * Ss + s_) * 128 + col];
    v = fmaxf(fmaf(v, scl, shf), 0.f);
    m = fmaxf(m, v);
  }
  feat[(size_t)bq * 128 + col] = m;
}

// ---------------- final: q-norm, logits, coalesced transpose-assemble -------
__global__ __launch_bounds__(512) void final2(const float* __restrict__ net,
                                              const float* __restrict__ qbuf,
                                              const float* __restrict__ tn,
                                              float* __restrict__ out) {
  __shared__ float tile[79][65];
  const int blk = blockIdx.x;  // 128 blocks, 64 rows each
  const int tid = threadIdx.x;
  const int r = tid >> 3, oct = tid & 7;
  const int row = blk * 64 + r;
  const int b = (blk * 64) >> 9, p0 = (blk * 64) & 511;

  const float* qr = qbuf + (size_t)row * 512 + oct * 64;
  float4 q4[16];
  #pragma unroll
  for (int i = 0; i < 16; i++) q4[i] = *(const float4*)(qr + 4 * i);
  float ss = 0.f;
  float dot[10];
  #pragma unroll
  for (int t = 0; t < 10; t++) dot[t] = 0.f;
  #pragma unroll
  for (int i = 0; i < 16; i++) {
    float4 a = q4[i];
    ss += a.x * a.x + a.y * a.y + a.z * a.z + a.w * a.w;
    #pragma unroll
    for (int t = 0; t < 10; t++) {
      float4 b4 = *(const float4*)(tn + (size_t)t * 512 + oct * 64 + i * 4);
      dot[t] += a.x * b4.x + a.y * b4.y + a.z * b4.z + a.w * b4.w;
    }
  }
  #pragma unroll
  for (int off = 1; off < 8; off <<= 1) {
    ss += __shfl_xor(ss, off, 8);
    #pragma unroll
    for (int t = 0; t < 10; t++) dot[t] += __shfl_xor(dot[t], off, 8);
  }
  if (oct == 0) {
    float inv = rsqrtf(ss) * (1.f / 0.07f);
    #pragma unroll
    for (int t = 0; t < 10; t++) tile[69 + t][r] = dot[t] * inv;
  }
  for (int idx = tid; idx < 64 * 69; idx += 512) {
    int r2 = idx / 69, ch = idx - 69 * r2;
    tile[ch][r2] = net[(size_t)(blk * 64 + r2) * 325 + ch];
  }
  __syncthreads();
  for (int idx = tid; idx < 79 * 64; idx += 512) {
    int ch = idx >> 6, rr = idx & 63;
    out[((size_t)b * 79 + ch) * 512 + p0 + rr] = tile[ch][rr];
  }
}

extern "C" void kernel_launch(void* const* d_in, const int* in_sizes, int n_in,
                              void* d_out, int out_size, void* d_ws,
                              size_t ws_size, hipStream_t stream) {
  const float* xyz = (const float*)d_in[0];
  const float* features = (const float*)d_in[1];
  const float* text = (const float*)d_in[2];
  const float* g_w0 = (const float*)d_in[3];
  const float* g_w1 = (const float*)d_in[4];
  const float* g_w2 = (const float*)d_in[5];
  const float* g_gam0 = (const float*)d_in[6];
  const float* g_bet0 = (const float*)d_in[7];
  const float* g_gam1 = (const float*)d_in[8];
  const float* g_bet1 = (const float*)d_in[9];
  const float* g_gam2 = (const float*)d_in[10];
  const float* g_bet2 = (const float*)d_in[11];
  const float* conv1_w = (const float*)d_in[12];
  const float* conv1_b = (const float*)d_in[13];
  const float* bn1_g = (const float*)d_in[14];
  const float* bn1_b = (const float*)d_in[15];
  const float* conv2_w = (const float*)d_in[16];
  const float* conv2_b = (const float*)d_in[17];
  const float* bn2_g = (const float*)d_in[18];
  const float* bn2_b = (const float*)d_in[19];
  const float* conv3_w = (const float*)d_in[20];
  const float* conv3_b = (const float*)d_in[21];
  const float* h_w0 = (const float*)d_in[22];
  const float* h_b0 = (const float*)d_in[23];
  const float* h_g0 = (const float*)d_in[24];
  const float* h_be0 = (const float*)d_in[25];
  const float* h_w1 = (const float*)d_in[26];
  const float* h_b1 = (const float*)d_in[27];
  const float* h_g1 = (const float*)d_in[28];
  const float* h_be1 = (const float*)d_in[29];
  const float* h_w2 = (const float*)d_in[30];
  const float* h_b2 = (const float*)d_in[31];
  float* out = (float*)d_out;
  char* ws = (char*)d_ws;

  float* tn = (float*)(ws + OFF_TNORM);
  float* sums = (float*)(ws + OFF_SUMS);
  int* inds = (int*)(ws + OFF_INDS);
  int* idxl = (int*)(ws + OFF_IDXL);
  float* gx = (float*)(ws + OFF_GX);
  float* F1 = (float*)(ws + OFF_F1);
  float* BIGA = (float*)(ws + OFF_BIGA);
  float* BIGB = (float*)(ws + OFF_BIGB);
  float* feat = (float*)(ws + OFF_FEAT);
  float* c1 = (float*)(ws + OFF_C1);
  float* c2 = (float*)(ws + OFF_C2);
  float* net = (float*)(ws + OFF_NET);

  hipMemsetAsync(sums, 0, 16384, stream);
  fused_pre<<<529, 256, 0, stream>>>(xyz, inds, features, g_w0, F1, text, tn);
  neigh_k<<<2048, 256, 0, stream>>>(xyz, inds, idxl, gx);
  gather_l1<<<2048, 256, 0, stream>>>(F1, idxl, gx, g_w0, BIGA, sums + SB0S,
                                      sums + SB0Q);
  gemm_f32<128, true, false, true><<<dim3(2048, 1), 256, 0, stream>>>(
      BIGA, 128, g_w1, 128, nullptr, sums + SB0S, sums + SB0Q, 1.f / 131072.f,
      g_gam0, g_bet0, BIGB, 128, sums + SB1S, sums + SB1Q);
  gemm_f32<128, true, false, true><<<dim3(2048, 1), 256, 0, stream>>>(
      BIGB, 128, g_w2, 128, nullptr, sums + SB1S, sums + SB1Q, 1.f / 131072.f,
      g_gam1, g_bet1, BIGA, 128, sums + SB2S, sums + SB2Q);
  maxpool_bn<<<4096, 256, 0, stream>>>(BIGA, sums + SB2S, sums + SB2Q, g_gam2,
                                       g_bet2, feat);
  gemm_f32<128, false, true, true><<<dim3(128, 1), 256, 0, stream>>>(
      feat, 128, conv1_w, 128, conv1_b, nullptr, nullptr, 0.f, nullptr,
      nullptr, c1, 128, sums + SC1S, sums + SC1Q);
  gemm_f32<128, true, true, true><<<dim3(128, 1), 256, 0, stream>>>(
      c1, 128, conv2_w, 128, conv2_b, sums + SC1S, sums + SC1Q, 1.f / 8192.f,
      bn1_g, bn1_b, c2, 128, sums + SC2S, sums + SC2Q);
  gemm_f32<128, true, true, false><<<dim3(128, 3), 256, 0, stream>>>(
      c2, 128, conv3_w, 325, conv3_b, sums + SC2S, sums + SC2Q, 1.f / 8192.f,
      bn2_g, bn2_b, net, 325, nullptr, nullptr);
  gemm_f32<256, false, true, true><<<dim3(128, 4), 256, 0, stream>>>(
      net + 69, 325, h_w0, 512, h_b0, nullptr, nullptr, 0.f, nullptr, nullptr,
      BIGB, 512, sums + SH0S, sums + SH0Q);
  gemm_f32<512, true, true, true><<<dim3(128, 4), 256, 0, stream>>>(
      BIGB, 512, h_w1, 512, h_b1, sums + SH0S, sums + SH0Q, 1.f / 8192.f, h_g0,
      h_be0, BIGA, 512, sums + SH1S, sums + SH1Q);
  gemm_f32<512, true, true, false><<<dim3(128, 4), 256, 0, stream>>>(
      BIGA, 512, h_w2, 512, h_b2, sums + SH1S, sums + SH1Q, 1.f / 8192.f, h_g1,
      h_be1, BIGB, 512, nullptr, nullptr);
  final2<<<128, 512, 0, stream>>>(net, BIGB, tn, out);
}

// Round 6
// 1052.519 us; speedup vs baseline: 1.7903x; 1.1103x over previous
//
#include <hip/hip_runtime.h>
#include <hip/hip_bf16.h>
#include <cstdint>
#include <cstddef>

#define Bb 16
#define Kk 2048
#define Pp 512
#define Ss 16
#define Cc 256
#define HEADOUT 325

typedef __attribute__((ext_vector_type(8))) short bf16x8;
typedef __attribute__((ext_vector_type(4))) float f32x4;

__device__ __forceinline__ unsigned short f2bf(float x) {  // RNE
  unsigned u = __float_as_uint(x);
  u = (u + 0x7FFF + ((u >> 16) & 1)) >> 16;
  return (unsigned short)u;
}
__device__ __forceinline__ float bf2f(unsigned short s) {
  return __uint_as_float((unsigned)s << 16);
}
// truncation split: x ≈ hi + lo with |x-hi-lo| <= 2^-16 |x|
__device__ __forceinline__ void split2(float x, short& h, short& l) {
  unsigned u = __float_as_uint(x);
  h = (short)(u >> 16);
  float r = x - __uint_as_float(u & 0xFFFF0000u);
  l = (short)(__float_as_uint(r) >> 16);
}

// ---------------- workspace layout (bytes) ----------------
static constexpr size_t OFF_TNORM = 0;                          // 20480
static constexpr size_t OFF_SUMS  = 20480;                      // 16384
static constexpr size_t OFF_INDS  = 36864;                      // 32768
static constexpr size_t OFF_IDXL  = 69632;                      // 524288
static constexpr size_t OFF_GX    = 593920;                     // 1572864
static constexpr size_t OFF_F1    = 2166784;                    // 16777216 f32
static constexpr size_t OFF_BIGA  = 18944000;                   // 67108864 f32
static constexpr size_t OFF_BIGB  = 86052864;                   // 67108864 f32
static constexpr size_t OFF_NET   = 153161728;                  // 10649600 f32
static constexpr size_t OFF_WTH   = 163811328;                  // 1441792 bf16
static constexpr size_t OFF_WTL   = 165253120;                  // 1441792 bf16
// aliases inside BIGB (dead after L3 gemm consumes it):
//   FEAT  = BIGB+0        (8192x128 f32, 4MB)
//   C1F   = BIGB+4194304
//   C2F   = BIGB+8388608
//   CLIPF = BIGB+12582912 (8192x256 f32, 8MB)
// aliases inside BIGA (dead after maxpool consumes it):
//   H0F = BIGA+0, H1F = BIGA+16777216, QF = BIGA+33554432

// Wt element offsets
#define WT_GW1 0
#define WT_GW2 16384
#define WT_C1  32768
#define WT_C2  49152
#define WT_H0  65536
#define WT_H1  196608
#define WT_H2  458752

// sum-slot float offsets inside OFF_SUMS
#define SB0S 0
#define SB0Q 128
#define SB1S 256
#define SB1Q 384
#define SB2S 512
#define SB2Q 640
#define SC1S 768
#define SC1Q 896
#define SC2S 1024
#define SC2Q 1152
#define SH0S 1280
#define SH0Q 1792
#define SH1S 2304
#define SH1Q 2816

template <int CTRL>
__device__ __forceinline__ float fmax_dpp(float v) {
  int o = __builtin_amdgcn_update_dpp(0, __float_as_int(v), CTRL, 0xF, 0xF, true);
  return fmaxf(v, __int_as_float(o));
}

// ---- fused: fps (0..15) | F1 gemm (16..527) | tnorm (528) | wprep (529..535)
__global__ __launch_bounds__(256, 1) void fused_pre(
    const float* __restrict__ xyz, int* __restrict__ inds,
    const float* __restrict__ features, const float* __restrict__ g_w0,
    float* __restrict__ F1, const float* __restrict__ text,
    float* __restrict__ tn, const float* __restrict__ g_w1,
    const float* __restrict__ g_w2, const float* __restrict__ conv1_w,
    const float* __restrict__ conv2_w, const float* __restrict__ h_w0,
    const float* __restrict__ h_w1, const float* __restrict__ h_w2,
    unsigned short* __restrict__ wth, unsigned short* __restrict__ wtl) {
  __shared__ __align__(16) float smem[8208];
  const int tid = threadIdx.x;

  if (blockIdx.x < 16) {
    // ===== FPS: 4 waves, thread-major k = tid*8+j ==========================
    #pragma clang fp contract(off)
    const int b = blockIdx.x;
    float4* pt4 = (float4*)smem;
    unsigned long long (*redw)[4] = (unsigned long long(*)[4])(smem + 8192);
    const float* base = xyz + (size_t)b * Kk * 3;
    for (int i = tid; i < Kk; i += 256) {
      pt4[i] = make_float4(base[3 * i], base[3 * i + 1], base[3 * i + 2], 0.f);
    }
    if (tid == 0) inds[b * Pp] = 0;
    float cx[8], cy[8], cz[8], dm[8];
    {
      const float* pb = base + tid * 24;
      float4 f0 = *(const float4*)(pb + 0);
      float4 f1 = *(const float4*)(pb + 4);
      float4 f2 = *(const float4*)(pb + 8);
      float4 f3 = *(const float4*)(pb + 12);
      float4 f4 = *(const float4*)(pb + 16);
      float4 f5 = *(const float4*)(pb + 20);
      cx[0] = f0.x; cy[0] = f0.y; cz[0] = f0.z;
      cx[1] = f0.w; cy[1] = f1.x; cz[1] = f1.y;
      cx[2] = f1.z; cy[2] = f1.w; cz[2] = f2.x;
      cx[3] = f2.y; cy[3] = f2.z; cz[3] = f2.w;
      cx[4] = f3.x; cy[4] = f3.y; cz[4] = f3.z;
      cx[5] = f3.w; cy[5] = f4.x; cz[5] = f4.y;
      cx[6] = f4.z; cy[6] = f4.w; cz[6] = f5.x;
      cx[7] = f5.y; cy[7] = f5.z; cz[7] = f5.w;
      #pragma unroll
      for (int j = 0; j < 8; j++) dm[j] = 1e10f;
    }
    __syncthreads();
    const int lane = tid & 63, wid = tid >> 6;
    int last = 0;
    for (int it = 1; it < Pp; ++it) {
      float4 L = pt4[last];
      float bf = -1.f;
      int bj = 0;
      #pragma unroll
      for (int j = 0; j < 8; j++) {
        float dx = cx[j] - L.x, dy = cy[j] - L.y, dz = cz[j] - L.z;
        float d = (dx * dx + dy * dy) + dz * dz;
        float m2 = fminf(dm[j], d);
        dm[j] = m2;
        if (m2 > bf) { bf = m2; bj = j; }
      }
      float g = bf;
      g = fmax_dpp<0xB1>(g);
      g = fmax_dpp<0x4E>(g);
      g = fmax_dpp<0x141>(g);
      g = fmax_dpp<0x140>(g);
      g = fmaxf(g, __shfl_xor(g, 16, 64));
      g = fmaxf(g, __shfl_xor(g, 32, 64));
      unsigned long long msk = __ballot(bf == g);
      int src = __builtin_ctzll(msk);
      int kk = (tid << 3) | bj;
      int kwin = __shfl(kk, src, 64);
      if (lane == 0)
        redw[it & 1][wid] = ((unsigned long long)__float_as_uint(g) << 32) |
                            (unsigned)(~(unsigned)kwin);
      __syncthreads();
      unsigned long long q0 = redw[it & 1][0], q1 = redw[it & 1][1];
      unsigned long long q2 = redw[it & 1][2], q3 = redw[it & 1][3];
      unsigned long long m0 = q0 > q1 ? q0 : q1;
      unsigned long long m1 = q2 > q3 ? q2 : q3;
      unsigned long long mm = m0 > m1 ? m0 : m1;
      last = (int)(~(unsigned)mm);
      if (tid == 0) inds[b * Pp + it] = last;
    }
  } else if (blockIdx.x == 528) {
    // ===== text-feature normalization ======================================
    int w = tid >> 6, lane = tid & 63;
    for (int r = w; r < 10; r += 4) {
      const float* rw = text + (size_t)r * 512;
      float v[8];
      float ss = 0.f;
      #pragma unroll
      for (int u = 0; u < 8; u++) { v[u] = rw[lane + 64 * u]; ss += v[u] * v[u]; }
      #pragma unroll
      for (int off = 32; off; off >>= 1) ss += __shfl_xor(ss, off, 64);
      float nrm = sqrtf(ss);
      #pragma unroll
      for (int u = 0; u < 8; u++)
        tn[(size_t)r * 512 + lane + 64 * u] = v[u] / nrm;
    }
  } else if (blockIdx.x >= 529) {
    // ===== weight transpose + RNE bf16 split: Wh+Wl[n][k] ~= W[k][n] ======
    int wi = blockIdx.x - 529;
    const float* W;
    int K, N;
    unsigned short *dh, *dl;
    switch (wi) {
      case 0: W = g_w1;    K = 128; N = 128; dh = wth + WT_GW1; dl = wtl + WT_GW1; break;
      case 1: W = g_w2;    K = 128; N = 128; dh = wth + WT_GW2; dl = wtl + WT_GW2; break;
      case 2: W = conv1_w; K = 128; N = 128; dh = wth + WT_C1;  dl = wtl + WT_C1;  break;
      case 3: W = conv2_w; K = 128; N = 128; dh = wth + WT_C2;  dl = wtl + WT_C2;  break;
      case 4: W = h_w0;    K = 256; N = 512; dh = wth + WT_H0;  dl = wtl + WT_H0;  break;
      case 5: W = h_w1;    K = 512; N = 512; dh = wth + WT_H1;  dl = wtl + WT_H1;  break;
      default: W = h_w2;   K = 512; N = 512; dh = wth + WT_H2;  dl = wtl + WT_H2;  break;
    }
    for (int idx = tid; idx < K * N; idx += 256) {
      int k = idx / N, n = idx - k * N;
      float w = W[idx];
      unsigned short hi = f2bf(w);
      unsigned short lo = f2bf(w - bf2f(hi));
      dh[n * K + k] = hi;
      dl[n * K + k] = lo;
    }
  } else {
    // ===== F1 = feats_kc @ g_w0[3:,:]  (32768 x 256 x 128) ================
    float (*a_t)[68] = (float(*)[68])smem;
    float (*b_t)[128] = (float(*)[128])(smem + 32 * 68);
    const float* W = g_w0 + 3 * 128;
    const int m0 = (blockIdx.x - 16) * 64;
    float acc[4][8];
    #pragma unroll
    for (int i = 0; i < 4; i++)
      #pragma unroll
      for (int j = 0; j < 8; j++) acc[i][j] = 0.f;
    const int ty = tid >> 4, tx = tid & 15;
    const int lr = tid & 63, wv = tid >> 6;
    const int bb = m0 >> 11, k0 = m0 & 2047;
    const float* fb = features + (size_t)bb * (Cc * Kk);
    for (int c0 = 0; c0 < 256; c0 += 32) {
      #pragma unroll
      for (int i = 0; i < 8; i++) {
        int c = c0 + wv + 4 * i;
        a_t[wv + 4 * i][lr] = fb[(size_t)c * Kk + k0 + lr];
      }
      #pragma unroll
      for (int p = 0; p < 4; p++) {
        int cc = p * 8 + (tid >> 5);
        int nl = (tid & 31) * 4;
        *(float4*)&b_t[cc][nl] = *(const float4*)&W[(size_t)(c0 + cc) * 128 + nl];
      }
      __syncthreads();
      #pragma unroll
      for (int kk = 0; kk < 32; kk++) {
        float4 av = *(const float4*)&a_t[kk][ty * 4];
        float4 b0 = *(const float4*)&b_t[kk][tx * 4];
        float4 b1 = *(const float4*)&b_t[kk][tx * 4 + 64];
        float ap[4] = {av.x, av.y, av.z, av.w};
        float bq0[4] = {b0.x, b0.y, b0.z, b0.w};
        float bq1[4] = {b1.x, b1.y, b1.z, b1.w};
        #pragma unroll
        for (int i = 0; i < 4; i++) {
          #pragma unroll
          for (int u = 0; u < 4; u++) {
            acc[i][u] = fmaf(ap[i], bq0[u], acc[i][u]);
            acc[i][4 + u] = fmaf(ap[i], bq1[u], acc[i][4 + u]);
          }
        }
      }
      __syncthreads();
    }
    #pragma unroll
    for (int i = 0; i < 4; i++) {
      size_t mrow = (size_t)(m0 + ty * 4 + i);
      #pragma unroll
      for (int gq = 0; gq < 2; gq++) {
        float4 v4 = make_float4(acc[i][gq * 4], acc[i][gq * 4 + 1],
                                acc[i][gq * 4 + 2], acc[i][gq * 4 + 3]);
        *(float4*)&F1[mrow * 128 + gq * 64 + tx * 4] = v4;
      }
    }
  }
}

// ---------------- neighbor selection ----------------
__global__ __launch_bounds__(256) void neigh_k(const float* __restrict__ xyz,
                                               const int* __restrict__ inds,
                                               int* __restrict__ idxl,
                                               float* __restrict__ gx) {
  int widx = blockIdx.x * 4 + (threadIdx.x >> 6);
  int lane = threadIdx.x & 63;
  int b = widx >> 9;
  int q = inds[widx];
  const float* base = xyz + (size_t)b * Kk * 3;
  float qx = base[3 * q], qy = base[3 * q + 1], qz = base[3 * q + 2];
  int cnt = 0;
  int myk = 0;
  for (int ch = 0; ch < 32 && cnt < Ss; ch++) {
    int k = ch * 64 + lane;
    float dx = base[3 * k] - qx;
    float dy = base[3 * k + 1] - qy;
    float dz = base[3 * k + 2] - qz;
    float d2 = __fadd_rn(__fadd_rn(__fmul_rn(dx, dx), __fmul_rn(dy, dy)),
                         __fmul_rn(dz, dz));
    unsigned long long m = __ballot(d2 < 0.09f);
    while (m && cnt < Ss) {
      int t = __builtin_ctzll(m);
      if (lane == cnt) myk = ch * 64 + t;
      cnt++;
      m &= m - 1;
    }
  }
  int first = __shfl(myk, 0, 64);
  if (lane < Ss) {
    int kk = (lane < cnt) ? myk : first;
    size_t o = (size_t)widx * Ss + lane;
    idxl[o] = kk;
    gx[o * 3 + 0] = (base[3 * kk] - qx) / 0.3f;
    gx[o * 3 + 1] = (base[3 * kk + 1] - qy) / 0.3f;
    gx[o * 3 + 2] = (base[3 * kk + 2] - qz) / 0.3f;
  }
}

// ------- split-bf16 MFMA GEMM: out = act_in(A) @ (Wh+Wl)^T (+bias), f32 -----
// A [M][KD] f32; Wh/Wl [N][KD] bf16.  3-term: Ah*Wh + Al*Wh + Ah*Wl.
// Block 4 waves, 128x128 tile (wave 64x64).
template <int KD, bool INBN, bool HASBIAS, bool OSUM>
__global__ __launch_bounds__(256, 2) void gemm_mfma(
    const float* __restrict__ A, const unsigned short* __restrict__ Wh,
    const unsigned short* __restrict__ Wl, const float* __restrict__ bias,
    const float* __restrict__ isum, const float* __restrict__ isq,
    float inv_cnt, const float* __restrict__ gamma,
    const float* __restrict__ beta, float* __restrict__ outp, int N,
    float* __restrict__ osum, float* __restrict__ osq) {
  __shared__ float sc[INBN ? KD : 1];
  __shared__ float sh[INBN ? KD : 1];
  __shared__ float red_s[OSUM ? 128 : 1];
  __shared__ float red_q[OSUM ? 128 : 1];
  const int tid = threadIdx.x;
  if (INBN) {
    for (int c = tid; c < KD; c += 256) {
      float mean = isum[c] * inv_cnt;
      float var = isq[c] * inv_cnt - mean * mean;
      float is_ = rsqrtf(var + 1e-5f);
      float scl = gamma[c] * is_;
      sc[c] = scl;
      sh[c] = beta[c] - mean * scl;
    }
  }
  if (OSUM && tid < 128) { red_s[tid] = 0.f; red_q[tid] = 0.f; }
  __syncthreads();
  const int wave = tid >> 6, lane = tid & 63;
  const int wm = wave >> 1, wn = wave & 1;
  const int r = lane & 15, g = lane >> 4;
  const size_t m0 = (size_t)blockIdx.x * 128 + wm * 64;
  const int n0 = blockIdx.y * 128 + wn * 64;

  f32x4 acc[4][4] = {};
  for (int ks = 0; ks < KD / 32; ks++) {
    const int kb = ks * 32 + g * 8;
    bf16x8 bh[4], bl[4];
    #pragma unroll
    for (int nf = 0; nf < 4; nf++) {
      bh[nf] = *(const bf16x8*)&Wh[(size_t)(n0 + nf * 16 + r) * KD + kb];
      bl[nf] = *(const bf16x8*)&Wl[(size_t)(n0 + nf * 16 + r) * KD + kb];
    }
    float s8[8], h8[8];
    if (INBN) {
      #pragma unroll
      for (int j = 0; j < 8; j++) { s8[j] = sc[kb + j]; h8[j] = sh[kb + j]; }
    }
    #pragma unroll
    for (int mf = 0; mf < 4; mf++) {
      const float* ap = &A[(m0 + mf * 16 + r) * KD + kb];
      float4 x0 = *(const float4*)ap;
      float4 x1 = *(const float4*)(ap + 4);
      float xv[8] = {x0.x, x0.y, x0.z, x0.w, x1.x, x1.y, x1.z, x1.w};
      bf16x8 ah, al;
      #pragma unroll
      for (int j = 0; j < 8; j++) {
        float x = xv[j];
        if (INBN) x = fmaxf(fmaf(x, s8[j], h8[j]), 0.f);
        short hh, ll;
        split2(x, hh, ll);
        ah[j] = hh;
        al[j] = ll;
      }
      #pragma unroll
      for (int nf = 0; nf < 4; nf++) {
        acc[mf][nf] = __builtin_amdgcn_mfma_f32_16x16x32_bf16(
            ah, bh[nf], acc[mf][nf], 0, 0, 0);
        acc[mf][nf] = __builtin_amdgcn_mfma_f32_16x16x32_bf16(
            al, bh[nf], acc[mf][nf], 0, 0, 0);
        acc[mf][nf] = __builtin_amdgcn_mfma_f32_16x16x32_bf16(
            ah, bl[nf], acc[mf][nf], 0, 0, 0);
      }
    }
  }
  float bv[4];
  if (HASBIAS) {
    #pragma unroll
    for (int nf = 0; nf < 4; nf++) bv[nf] = bias[n0 + nf * 16 + r];
  }
  float ps[4] = {0.f, 0.f, 0.f, 0.f}, pq[4] = {0.f, 0.f, 0.f, 0.f};
  #pragma unroll
  for (int mf = 0; mf < 4; mf++) {
    #pragma unroll
    for (int nf = 0; nf < 4; nf++) {
      #pragma unroll
      for (int j = 0; j < 4; j++) {
        float v = acc[mf][nf][j];
        if (HASBIAS) v += bv[nf];
        size_t row = m0 + mf * 16 + g * 4 + j;
        int col = n0 + nf * 16 + r;
        if (OSUM) { ps[nf] += v; pq[nf] += v * v; }
        outp[row * N + col] = v;
      }
    }
  }
  if (OSUM) {
    #pragma unroll
    for (int nf = 0; nf < 4; nf++) {
      #pragma unroll
      for (int off = 16; off < 64; off <<= 1) {
        ps[nf] += __shfl_xor(ps[nf], off, 64);
        pq[nf] += __shfl_xor(pq[nf], off, 64);
      }
    }
    if (lane < 16) {
      #pragma unroll
      for (int nf = 0; nf < 4; nf++) {
        int lcol = wn * 64 + nf * 16 + r;
        atomicAdd(&red_s[lcol], ps[nf]);
        atomicAdd(&red_q[lcol], pq[nf]);
      }
    }
    __syncthreads();
    if (tid < 128) {
      atomicAdd(&osum[blockIdx.y * 128 + tid], red_s[tid]);
      atomicAdd(&osq[blockIdx.y * 128 + tid], red_q[tid]);
    }
  }
}

// ---------------- f32 SIMD GEMM (conv3 only: N=325, + clip_in f32 emit) -----
template <int KD, bool INBN, bool HASBIAS, bool WCLIP>
__global__ __launch_bounds__(256) void gemm_f32(
    const float* __restrict__ A, int lda, const float* __restrict__ W, int N,
    const float* __restrict__ bias, const float* __restrict__ isum,
    const float* __restrict__ isq, float inv_cnt,
    const float* __restrict__ gamma, const float* __restrict__ beta,
    float* __restrict__ Cout, int ldc, float* __restrict__ clipf) {
  __shared__ float a_t[32][68];
  __shared__ float b_t[32][128];
  __shared__ float sc[INBN ? KD : 1];
  __shared__ float sh[INBN ? KD : 1];
  const int tid = threadIdx.x;
  const int m0 = blockIdx.x * 64;
  const int n0 = blockIdx.y * 128;
  if (INBN) {
    for (int c = tid; c < KD; c += 256) {
      float mean = isum[c] * inv_cnt;
      float var = isq[c] * inv_cnt - mean * mean;
      float is_ = rsqrtf(var + 1e-5f);
      float scl = gamma[c] * is_;
      sc[c] = scl;
      sh[c] = beta[c] - mean * scl;
    }
    __syncthreads();
  }
  float acc[4][8];
  #pragma unroll
  for (int i = 0; i < 4; i++)
    #pragma unroll
    for (int j = 0; j < 8; j++) acc[i][j] = 0.f;
  const int ty = tid >> 4, tx = tid & 15;
  for (int c0 = 0; c0 < KD; c0 += 32) {
    {
      const int lr = tid >> 2, lcs = tid & 3;
      #pragma unroll
      for (int i = 0; i < 8; i++) {
        int c = c0 + lcs + 4 * i;
        float v = A[(size_t)(m0 + lr) * lda + c];
        if (INBN) v = fmaxf(fmaf(v, sc[c], sh[c]), 0.f);
        a_t[lcs + 4 * i][lr] = v;
      }
    }
    {
      #pragma unroll
      for (int p = 0; p < 4; p++) {
        int cc = p * 8 + (tid >> 5);
        int nl = (tid & 31) * 4;
        #pragma unroll
        for (int u = 0; u < 4; u++) {
          int n = n0 + nl + u;
          b_t[cc][nl + u] = (n < N) ? W[(size_t)(c0 + cc) * N + n] : 0.f;
        }
      }
    }
    __syncthreads();
    #pragma unroll
    for (int kk = 0; kk < 32; kk++) {
      float4 av = *(const float4*)&a_t[kk][ty * 4];
      float4 b0 = *(const float4*)&b_t[kk][tx * 4];
      float4 b1 = *(const float4*)&b_t[kk][tx * 4 + 64];
      float ap[4] = {av.x, av.y, av.z, av.w};
      float bq0[4] = {b0.x, b0.y, b0.z, b0.w};
      float bq1[4] = {b1.x, b1.y, b1.z, b1.w};
      #pragma unroll
      for (int i = 0; i < 4; i++) {
        #pragma unroll
        for (int u = 0; u < 4; u++) {
          acc[i][u] = fmaf(ap[i], bq0[u], acc[i][u]);
          acc[i][4 + u] = fmaf(ap[i], bq1[u], acc[i][4 + u]);
        }
      }
    }
    __syncthreads();
  }
  #pragma unroll
  for (int i = 0; i < 4; i++) {
    size_t m = (size_t)(m0 + ty * 4 + i);
    #pragma unroll
    for (int gq = 0; gq < 2; gq++) {
      #pragma unroll
      for (int u = 0; u < 4; u++) {
        int n = n0 + gq * 64 + tx * 4 + u;
        if (n < N) {
          float v = acc[i][gq * 4 + u];
          if (HASBIAS) v += bias[n];
          Cout[m * ldc + n] = v;
          if (WCLIP && n >= 69) clipf[m * 256 + (n - 69)] = v;
        }
      }
    }
  }
}

// ---------------- gather layer-1 (f32 out + bn0 sums) ----------------
__global__ __launch_bounds__(256) void gather_l1(
    const float* __restrict__ F1, const int* __restrict__ idxl,
    const float* __restrict__ gx, const float* __restrict__ g_w0,
    float* __restrict__ L1, float* __restrict__ s0, float* __restrict__ q0) {
  int col = threadIdx.x & 127, half = threadIdx.x >> 7;
  int row0 = blockIdx.x * 64 + half * 32;
  float w0 = g_w0[col], w1 = g_w0[128 + col], w2 = g_w0[256 + col];
  __shared__ float rs[128], rq[128];
  if (threadIdx.x < 128) { rs[threadIdx.x] = 0.f; rq[threadIdx.x] = 0.f; }
  __syncthreads();
  float s = 0.f, q = 0.f;
  for (int rr = 0; rr < 32; rr++) {
    int row = row0 + rr;
    int b = row >> 13;
    int idx = idxl[row];
    float g0 = gx[(size_t)row * 3], g1 = gx[(size_t)row * 3 + 1],
          g2 = gx[(size_t)row * 3 + 2];
    float v = F1[((size_t)(b * Kk + idx)) * 128 + col] + g0 * w0 + g1 * w1 +
              g2 * w2;
    L1[(size_t)row * 128 + col] = v;
    s += v;
    q += v * v;
  }
  atomicAdd(&rs[col], s);
  atomicAdd(&rq[col], q);
  __syncthreads();
  if (threadIdx.x < 128) {
    atomicAdd(&s0[threadIdx.x], rs[threadIdx.x]);
    atomicAdd(&q0[threadIdx.x], rq[threadIdx.x]);
  }
}

// ---------------- bn + relu + max over S ----------------
__global__ __launch_bounds__(256) void maxpool_bn(
    const float* __restrict__ L3, const float* __restrict__ s2,
    const float* __restrict__ q2, const float* __restrict__ gam,
    const float* __restrict__ bet, float* __restrict__ feat) {
  int col = threadIdx.x & 127, half = threadIdx.x >> 7;
  int bq = blockIdx.x * 2 + half;
  float mean = s2[col] * (1.f / 131072.f);
  float var = q2[col] * (1.f / 131072.f) - mean * mean;
  float is_ = rsqrtf(var + 1e-5f);
  float scl = gam[col] * is_, shf = bet[col] - mean * scl;
  float m = -1e30f;
  #pragma unroll
  for (int s_ = 0; s_ < Ss; s_++) {
    float v = L3[((size_t)bq * Ss + s_) * 128 + col];
    v = fmaxf(fmaf(v, scl, shf), 0.f);
    m = fmaxf(m, v);
  }
  feat[(size_t)bq * 128 + col] = m;
}

// ---------------- final: q-norm, logits, coalesced transpose-assemble -------
__global__ __launch_bounds__(512) void final2(const float* __restrict__ net,
                                              const float* __restrict__ qbuf,
                                              const float* __restrict__ tn,
                                              float* __restrict__ out) {
  __shared__ float tile[79][65];
  const int blk = blockIdx.x;
  const int tid = threadIdx.x;
  const int r = tid >> 3, oct = tid & 7;
  const int row = blk * 64 + r;
  const int b = (blk * 64) >> 9, p0 = (blk * 64) & 511;

  const float* qr = qbuf + (size_t)row * 512 + oct * 64;
  float4 q4[16];
  #pragma unroll
  for (int i = 0; i < 16; i++) q4[i] = *(const float4*)(qr + 4 * i);
  float ss = 0.f;
  float dot[10];
  #pragma unroll
  for (int t = 0; t < 10; t++) dot[t] = 0.f;
  #pragma unroll
  for (int i = 0; i < 16; i++) {
    float4 a = q4[i];
    ss += a.x * a.x + a.y * a.y + a.z * a.z + a.w * a.w;
    #pragma unroll
    for (int t = 0; t < 10; t++) {
      float4 b4 = *(const float4*)(tn + (size_t)t * 512 + oct * 64 + i * 4);
      dot[t] += a.x * b4.x + a.y * b4.y + a.z * b4.z + a.w * b4.w;
    }
  }
  #pragma unroll
  for (int off = 1; off < 8; off <<= 1) {
    ss += __shfl_xor(ss, off, 8);
    #pragma unroll
    for (int t = 0; t < 10; t++) dot[t] += __shfl_xor(dot[t], off, 8);
  }
  if (oct == 0) {
    float inv = rsqrtf(ss) * (1.f / 0.07f);
    #pragma unroll
    for (int t = 0; t < 10; t++) tile[69 + t][r] = dot[t] * inv;
  }
  for (int idx = tid; idx < 64 * 69; idx += 512) {
    int r2 = idx / 69, ch = idx - 69 * r2;
    tile[ch][r2] = net[(size_t)(blk * 64 + r2) * 325 + ch];
  }
  __syncthreads();
  for (int idx = tid; idx < 79 * 64; idx += 512) {
    int ch = idx >> 6, rr = idx & 63;
    out[((size_t)b * 79 + ch) * 512 + p0 + rr] = tile[ch][rr];
  }
}

extern "C" void kernel_launch(void* const* d_in, const int* in_sizes, int n_in,
                              void* d_out, int out_size, void* d_ws,
                              size_t ws_size, hipStream_t stream) {
  const float* xyz = (const float*)d_in[0];
  const float* features = (const float*)d_in[1];
  const float* text = (const float*)d_in[2];
  const float* g_w0 = (const float*)d_in[3];
  const float* g_w1 = (const float*)d_in[4];
  const float* g_w2 = (const float*)d_in[5];
  const float* g_gam0 = (const float*)d_in[6];
  const float* g_bet0 = (const float*)d_in[7];
  const float* g_gam1 = (const float*)d_in[8];
  const float* g_bet1 = (const float*)d_in[9];
  const float* g_gam2 = (const float*)d_in[10];
  const float* g_bet2 = (const float*)d_in[11];
  const float* conv1_w = (const float*)d_in[12];
  const float* conv1_b = (const float*)d_in[13];
  const float* bn1_g = (const float*)d_in[14];
  const float* bn1_b = (const float*)d_in[15];
  const float* conv2_w = (const float*)d_in[16];
  const float* conv2_b = (const float*)d_in[17];
  const float* bn2_g = (const float*)d_in[18];
  const float* bn2_b = (const float*)d_in[19];
  const float* conv3_w = (const float*)d_in[20];
  const float* conv3_b = (const float*)d_in[21];
  const float* h_w0 = (const float*)d_in[22];
  const float* h_b0 = (const float*)d_in[23];
  const float* h_g0 = (const float*)d_in[24];
  const float* h_be0 = (const float*)d_in[25];
  const float* h_w1 = (const float*)d_in[26];
  const float* h_b1 = (const float*)d_in[27];
  const float* h_g1 = (const float*)d_in[28];
  const float* h_be1 = (const float*)d_in[29];
  const float* h_w2 = (const float*)d_in[30];
  const float* h_b2 = (const float*)d_in[31];
  float* out = (float*)d_out;
  char* ws = (char*)d_ws;

  float* tn = (float*)(ws + OFF_TNORM);
  float* sums = (float*)(ws + OFF_SUMS);
  int* inds = (int*)(ws + OFF_INDS);
  int* idxl = (int*)(ws + OFF_IDXL);
  float* gx = (float*)(ws + OFF_GX);
  float* F1 = (float*)(ws + OFF_F1);
  float* BIGA = (float*)(ws + OFF_BIGA);
  float* BIGB = (float*)(ws + OFF_BIGB);
  float* FEAT = (float*)(ws + OFF_BIGB);
  float* C1F = (float*)(ws + OFF_BIGB + 4194304);
  float* C2F = (float*)(ws + OFF_BIGB + 8388608);
  float* CLIPF = (float*)(ws + OFF_BIGB + 12582912);
  float* H0F = (float*)(ws + OFF_BIGA);
  float* H1F = (float*)(ws + OFF_BIGA + 16777216);
  float* QF = (float*)(ws + OFF_BIGA + 33554432);
  float* net = (float*)(ws + OFF_NET);
  unsigned short* WTH = (unsigned short*)(ws + OFF_WTH);
  unsigned short* WTL = (unsigned short*)(ws + OFF_WTL);

  hipMemsetAsync(sums, 0, 16384, stream);
  fused_pre<<<536, 256, 0, stream>>>(xyz, inds, features, g_w0, F1, text, tn,
                                     g_w1, g_w2, conv1_w, conv2_w, h_w0, h_w1,
                                     h_w2, WTH, WTL);
  neigh_k<<<2048, 256, 0, stream>>>(xyz, inds, idxl, gx);
  gather_l1<<<2048, 256, 0, stream>>>(F1, idxl, gx, g_w0, BIGA, sums + SB0S,
                                      sums + SB0Q);
  // L2 = relu(bn0(L1)) @ g_w1   (131072 x 128 x 128, split-MFMA)
  gemm_mfma<128, true, false, true><<<dim3(1024, 1), 256, 0, stream>>>(
      BIGA, WTH + WT_GW1, WTL + WT_GW1, nullptr, sums + SB0S, sums + SB0Q,
      1.f / 131072.f, g_gam0, g_bet0, BIGB, 128, sums + SB1S, sums + SB1Q);
  // L3 = relu(bn1(L2)) @ g_w2
  gemm_mfma<128, true, false, true><<<dim3(1024, 1), 256, 0, stream>>>(
      BIGB, WTH + WT_GW2, WTL + WT_GW2, nullptr, sums + SB1S, sums + SB1Q,
      1.f / 131072.f, g_gam1, g_bet1, BIGA, 128, sums + SB2S, sums + SB2Q);
  // feat = max_s relu(bn2(L3))
  maxpool_bn<<<4096, 256, 0, stream>>>(BIGA, sums + SB2S, sums + SB2Q, g_gam2,
                                       g_bet2, FEAT);
  // c1 = feat @ conv1_w + b
  gemm_mfma<128, false, true, true><<<dim3(64, 1), 256, 0, stream>>>(
      FEAT, WTH + WT_C1, WTL + WT_C1, conv1_b, nullptr, nullptr, 0.f, nullptr,
      nullptr, C1F, 128, sums + SC1S, sums + SC1Q);
  // c2 = relu(bn(c1)) @ conv2_w + b
  gemm_mfma<128, true, true, true><<<dim3(64, 1), 256, 0, stream>>>(
      C1F, WTH + WT_C2, WTL + WT_C2, conv2_b, sums + SC1S, sums + SC1Q,
      1.f / 8192.f, bn1_g, bn1_b, C2F, 128, sums + SC2S, sums + SC2Q);
  // net = relu(bn(c2)) @ conv3_w + b   (N=325, f32 SIMD; emits clip_in f32)
  gemm_f32<128, true, true, true><<<dim3(128, 3), 256, 0, stream>>>(
      C2F, 128, conv3_w, 325, conv3_b, sums + SC2S, sums + SC2Q, 1.f / 8192.f,
      bn2_g, bn2_b, net, 325, CLIPF);
  // h0 = clip_in @ h_w0 + b
  gemm_mfma<256, false, true, true><<<dim3(64, 4), 256, 0, stream>>>(
      CLIPF, WTH + WT_H0, WTL + WT_H0, h_b0, nullptr, nullptr, 0.f, nullptr,
      nullptr, H0F, 512, sums + SH0S, sums + SH0Q);
  // h1 = relu(bn(h0)) @ h_w1 + b
  gemm_mfma<512, true, true, true><<<dim3(64, 4), 256, 0, stream>>>(
      H0F, WTH + WT_H1, WTL + WT_H1, h_b1, sums + SH0S, sums + SH0Q,
      1.f / 8192.f, h_g0, h_be0, H1F, 512, sums + SH1S, sums + SH1Q);
  // q = relu(bn(h1)) @ h_w2 + b
  gemm_mfma<512, true, true, false><<<dim3(64, 4), 256, 0, stream>>>(
      H1F, WTH + WT_H2, WTL + WT_H2, h_b2, sums + SH1S, sums + SH1Q,
      1.f / 8192.f, h_g1, h_be1, QF, 512, nullptr, nullptr);
  final2<<<128, 512, 0, stream>>>(net, QF, tn, out);
}

// Round 7
// 848.807 us; speedup vs baseline: 2.2199x; 1.2400x over previous
//
#include <hip/hip_runtime.h>
#include <hip/hip_bf16.h>
#include <cstdint>
#include <cstddef>

#define Bb 16
#define Kk 2048
#define Pp 512
#define Ss 16
#define Cc 256
#define HEADOUT 325

typedef __attribute__((ext_vector_type(8))) short bf16x8;
typedef __attribute__((ext_vector_type(4))) float f32x4;

__device__ __forceinline__ unsigned short f2bf(float x) {  // RNE
  unsigned u = __float_as_uint(x);
  u = (u + 0x7FFF + ((u >> 16) & 1)) >> 16;
  return (unsigned short)u;
}
__device__ __forceinline__ float bf2f(unsigned short s) {
  return __uint_as_float((unsigned)s << 16);
}
// truncation split: x ~= hi + lo with |x-hi-lo| <= 2^-16 |x|
__device__ __forceinline__ void split2(float x, short& h, short& l) {
  unsigned u = __float_as_uint(x);
  h = (short)(u >> 16);
  float r = x - __uint_as_float(u & 0xFFFF0000u);
  l = (short)(__float_as_uint(r) >> 16);
}

// ---------------- workspace layout (bytes) ----------------
static constexpr size_t OFF_TNORM = 0;                          // 20480
static constexpr size_t OFF_SUMS  = 20480;                      // 16384
static constexpr size_t OFF_INDS  = 36864;                      // 32768
static constexpr size_t OFF_IDXL  = 69632;                      // 524288
static constexpr size_t OFF_GX    = 593920;                     // 1572864
static constexpr size_t OFF_F1    = 2166784;                    // 16777216 f32
static constexpr size_t OFF_BIGA  = 18944000;                   // 67108864 f32
static constexpr size_t OFF_BIGB  = 86052864;                   // 67108864 f32
static constexpr size_t OFF_NET   = 153161728;                  // 10649600 f32
static constexpr size_t OFF_WTH   = 163811328;                  // 1441792 bf16
static constexpr size_t OFF_WTL   = 165253120;                  // 1441792 bf16

// Wt element offsets
#define WT_GW1 0
#define WT_GW2 16384
#define WT_C1  32768
#define WT_C2  49152
#define WT_H0  65536
#define WT_H1  196608
#define WT_H2  458752

// sum-slot float offsets inside OFF_SUMS
#define SB0S 0
#define SB0Q 128
#define SB1S 256
#define SB1Q 384
#define SB2S 512
#define SB2Q 640
#define SC1S 768
#define SC1Q 896
#define SC2S 1024
#define SC2Q 1152
#define SH0S 1280
#define SH0Q 1792
#define SH1S 2304
#define SH1Q 2816

template <int CTRL>
__device__ __forceinline__ float fmax_dpp(float v) {
  int o = __builtin_amdgcn_update_dpp(0, __float_as_int(v), CTRL, 0xF, 0xF, true);
  return fmaxf(v, __int_as_float(o));
}

// fused: fps (0..15) | F1 gemm (16..527) | tnorm (528) | wprep (529..624)
__global__ __launch_bounds__(256, 1) void fused_pre(
    const float* __restrict__ xyz, int* __restrict__ inds,
    const float* __restrict__ features, const float* __restrict__ g_w0,
    float* __restrict__ F1, const float* __restrict__ text,
    float* __restrict__ tn, const float* __restrict__ g_w1,
    const float* __restrict__ g_w2, const float* __restrict__ conv1_w,
    const float* __restrict__ conv2_w, const float* __restrict__ h_w0,
    const float* __restrict__ h_w1, const float* __restrict__ h_w2,
    unsigned short* __restrict__ wth, unsigned short* __restrict__ wtl) {
  __shared__ __align__(16) float smem[8208];
  const int tid = threadIdx.x;

  if (blockIdx.x < 16) {
    // ===== FPS: 4 waves, thread-major k = tid*8+j ==========================
    #pragma clang fp contract(off)
    const int b = blockIdx.x;
    float4* pt4 = (float4*)smem;
    unsigned long long (*redw)[4] = (unsigned long long(*)[4])(smem + 8192);
    const float* base = xyz + (size_t)b * Kk * 3;
    for (int i = tid; i < Kk; i += 256) {
      pt4[i] = make_float4(base[3 * i], base[3 * i + 1], base[3 * i + 2], 0.f);
    }
    if (tid == 0) inds[b * Pp] = 0;
    float cx[8], cy[8], cz[8], dm[8];
    {
      const float* pb = base + tid * 24;
      float4 f0 = *(const float4*)(pb + 0);
      float4 f1 = *(const float4*)(pb + 4);
      float4 f2 = *(const float4*)(pb + 8);
      float4 f3 = *(const float4*)(pb + 12);
      float4 f4 = *(const float4*)(pb + 16);
      float4 f5 = *(const float4*)(pb + 20);
      cx[0] = f0.x; cy[0] = f0.y; cz[0] = f0.z;
      cx[1] = f0.w; cy[1] = f1.x; cz[1] = f1.y;
      cx[2] = f1.z; cy[2] = f1.w; cz[2] = f2.x;
      cx[3] = f2.y; cy[3] = f2.z; cz[3] = f2.w;
      cx[4] = f3.x; cy[4] = f3.y; cz[4] = f3.z;
      cx[5] = f3.w; cy[5] = f4.x; cz[5] = f4.y;
      cx[6] = f4.z; cy[6] = f4.w; cz[6] = f5.x;
      cx[7] = f5.y; cy[7] = f5.z; cz[7] = f5.w;
      #pragma unroll
      for (int j = 0; j < 8; j++) dm[j] = 1e10f;
    }
    __syncthreads();
    const int lane = tid & 63, wid = tid >> 6;
    int last = 0;
    for (int it = 1; it < Pp; ++it) {
      float4 L = pt4[last];
      float bf = -1.f;
      int bj = 0;
      #pragma unroll
      for (int j = 0; j < 8; j++) {
        float dx = cx[j] - L.x, dy = cy[j] - L.y, dz = cz[j] - L.z;
        float d = (dx * dx + dy * dy) + dz * dz;
        float m2 = fminf(dm[j], d);
        dm[j] = m2;
        if (m2 > bf) { bf = m2; bj = j; }
      }
      float g = bf;
      g = fmax_dpp<0xB1>(g);
      g = fmax_dpp<0x4E>(g);
      g = fmax_dpp<0x141>(g);
      g = fmax_dpp<0x140>(g);
      g = fmaxf(g, __shfl_xor(g, 16, 64));
      g = fmaxf(g, __shfl_xor(g, 32, 64));
      unsigned long long msk = __ballot(bf == g);
      int src = __builtin_ctzll(msk);
      int kk = (tid << 3) | bj;
      int kwin = __shfl(kk, src, 64);
      if (lane == 0)
        redw[it & 1][wid] = ((unsigned long long)__float_as_uint(g) << 32) |
                            (unsigned)(~(unsigned)kwin);
      __syncthreads();
      unsigned long long q0 = redw[it & 1][0], q1 = redw[it & 1][1];
      unsigned long long q2 = redw[it & 1][2], q3 = redw[it & 1][3];
      unsigned long long m0 = q0 > q1 ? q0 : q1;
      unsigned long long m1 = q2 > q3 ? q2 : q3;
      unsigned long long mm = m0 > m1 ? m0 : m1;
      last = (int)(~(unsigned)mm);
      if (tid == 0) inds[b * Pp + it] = last;
    }
  } else if (blockIdx.x == 528) {
    // ===== text-feature normalization ======================================
    int w = tid >> 6, lane = tid & 63;
    for (int r = w; r < 10; r += 4) {
      const float* rw = text + (size_t)r * 512;
      float v[8];
      float ss = 0.f;
      #pragma unroll
      for (int u = 0; u < 8; u++) { v[u] = rw[lane + 64 * u]; ss += v[u] * v[u]; }
      #pragma unroll
      for (int off = 32; off; off >>= 1) ss += __shfl_xor(ss, off, 64);
      float nrm = sqrtf(ss);
      #pragma unroll
      for (int u = 0; u < 8; u++)
        tn[(size_t)r * 512 + lane + 64 * u] = v[u] / nrm;
    }
  } else if (blockIdx.x >= 529) {
    // ===== weight transpose + RNE bf16 split (PARALLEL: 96 blocks) ========
    // blocks: 529+[0..3] g_w1 | [4..7] g_w2 | [8..11] conv1 | [12..15] conv2
    //         [16..31] h_w0 | [32..63] h_w1 | [64..95] h_w2
    int wb = blockIdx.x - 529;
    const float* W;
    int K, N, nblk, pidx;
    unsigned short *dh, *dl;
    if (wb < 4)       { W = g_w1;    K = 128; N = 128; dh = wth + WT_GW1; dl = wtl + WT_GW1; nblk = 4;  pidx = wb; }
    else if (wb < 8)  { W = g_w2;    K = 128; N = 128; dh = wth + WT_GW2; dl = wtl + WT_GW2; nblk = 4;  pidx = wb - 4; }
    else if (wb < 12) { W = conv1_w; K = 128; N = 128; dh = wth + WT_C1;  dl = wtl + WT_C1;  nblk = 4;  pidx = wb - 8; }
    else if (wb < 16) { W = conv2_w; K = 128; N = 128; dh = wth + WT_C2;  dl = wtl + WT_C2;  nblk = 4;  pidx = wb - 12; }
    else if (wb < 32) { W = h_w0;    K = 256; N = 512; dh = wth + WT_H0;  dl = wtl + WT_H0;  nblk = 16; pidx = wb - 16; }
    else if (wb < 64) { W = h_w1;    K = 512; N = 512; dh = wth + WT_H1;  dl = wtl + WT_H1;  nblk = 32; pidx = wb - 32; }
    else              { W = h_w2;    K = 512; N = 512; dh = wth + WT_H2;  dl = wtl + WT_H2;  nblk = 32; pidx = wb - 64; }
    for (int idx = pidx * 256 + tid; idx < K * N; idx += nblk * 256) {
      int k = idx / N, n = idx - k * N;
      float w = W[idx];
      unsigned short hi = f2bf(w);
      unsigned short lo = f2bf(w - bf2f(hi));
      dh[n * K + k] = hi;
      dl[n * K + k] = lo;
    }
  } else {
    // ===== F1 = feats_kc @ g_w0[3:,:]  (32768 x 256 x 128) ================
    float (*a_t)[68] = (float(*)[68])smem;
    float (*b_t)[128] = (float(*)[128])(smem + 32 * 68);
    const float* W = g_w0 + 3 * 128;
    const int m0 = (blockIdx.x - 16) * 64;
    float acc[4][8];
    #pragma unroll
    for (int i = 0; i < 4; i++)
      #pragma unroll
      for (int j = 0; j < 8; j++) acc[i][j] = 0.f;
    const int ty = tid >> 4, tx = tid & 15;
    const int lr = tid & 63, wv = tid >> 6;
    const int bb = m0 >> 11, k0 = m0 & 2047;
    const float* fb = features + (size_t)bb * (Cc * Kk);
    for (int c0 = 0; c0 < 256; c0 += 32) {
      #pragma unroll
      for (int i = 0; i < 8; i++) {
        int c = c0 + wv + 4 * i;
        a_t[wv + 4 * i][lr] = fb[(size_t)c * Kk + k0 + lr];
      }
      #pragma unroll
      for (int p = 0; p < 4; p++) {
        int cc = p * 8 + (tid >> 5);
        int nl = (tid & 31) * 4;
        *(float4*)&b_t[cc][nl] = *(const float4*)&W[(size_t)(c0 + cc) * 128 + nl];
      }
      __syncthreads();
      #pragma unroll
      for (int kk = 0; kk < 32; kk++) {
        float4 av = *(const float4*)&a_t[kk][ty * 4];
        float4 b0 = *(const float4*)&b_t[kk][tx * 4];
        float4 b1 = *(const float4*)&b_t[kk][tx * 4 + 64];
        float ap[4] = {av.x, av.y, av.z, av.w};
        float bq0[4] = {b0.x, b0.y, b0.z, b0.w};
        float bq1[4] = {b1.x, b1.y, b1.z, b1.w};
        #pragma unroll
        for (int i = 0; i < 4; i++) {
          #pragma unroll
          for (int u = 0; u < 4; u++) {
            acc[i][u] = fmaf(ap[i], bq0[u], acc[i][u]);
            acc[i][4 + u] = fmaf(ap[i], bq1[u], acc[i][4 + u]);
          }
        }
      }
      __syncthreads();
    }
    #pragma unroll
    for (int i = 0; i < 4; i++) {
      size_t mrow = (size_t)(m0 + ty * 4 + i);
      #pragma unroll
      for (int gq = 0; gq < 2; gq++) {
        float4 v4 = make_float4(acc[i][gq * 4], acc[i][gq * 4 + 1],
                                acc[i][gq * 4 + 2], acc[i][gq * 4 + 3]);
        *(float4*)&F1[mrow * 128 + gq * 64 + tx * 4] = v4;
      }
    }
  }
}

// ---------------- neighbor selection ----------------
__global__ __launch_bounds__(256) void neigh_k(const float* __restrict__ xyz,
                                               const int* __restrict__ inds,
                                               int* __restrict__ idxl,
                                               float* __restrict__ gx) {
  int widx = blockIdx.x * 4 + (threadIdx.x >> 6);
  int lane = threadIdx.x & 63;
  int b = widx >> 9;
  int q = inds[widx];
  const float* base = xyz + (size_t)b * Kk * 3;
  float qx = base[3 * q], qy = base[3 * q + 1], qz = base[3 * q + 2];
  int cnt = 0;
  int myk = 0;
  for (int ch = 0; ch < 32 && cnt < Ss; ch++) {
    int k = ch * 64 + lane;
    float dx = base[3 * k] - qx;
    float dy = base[3 * k + 1] - qy;
    float dz = base[3 * k + 2] - qz;
    float d2 = __fadd_rn(__fadd_rn(__fmul_rn(dx, dx), __fmul_rn(dy, dy)),
                         __fmul_rn(dz, dz));
    unsigned long long m = __ballot(d2 < 0.09f);
    while (m && cnt < Ss) {
      int t = __builtin_ctzll(m);
      if (lane == cnt) myk = ch * 64 + t;
      cnt++;
      m &= m - 1;
    }
  }
  int first = __shfl(myk, 0, 64);
  if (lane < Ss) {
    int kk = (lane < cnt) ? myk : first;
    size_t o = (size_t)widx * Ss + lane;
    idxl[o] = kk;
    gx[o * 3 + 0] = (base[3 * kk] - qx) / 0.3f;
    gx[o * 3 + 1] = (base[3 * kk + 1] - qy) / 0.3f;
    gx[o * 3 + 2] = (base[3 * kk + 2] - qz) / 0.3f;
  }
}

// ------- split-bf16 MFMA GEMM: out = act_in(A) @ (Wh+Wl)^T (+bias), f32 -----
template <int KD, bool INBN, bool HASBIAS, bool OSUM>
__global__ __launch_bounds__(256, 2) void gemm_mfma(
    const float* __restrict__ A, const unsigned short* __restrict__ Wh,
    const unsigned short* __restrict__ Wl, const float* __restrict__ bias,
    const float* __restrict__ isum, const float* __restrict__ isq,
    float inv_cnt, const float* __restrict__ gamma,
    const float* __restrict__ beta, float* __restrict__ outp, int N,
    float* __restrict__ osum, float* __restrict__ osq) {
  __shared__ float sc[INBN ? KD : 1];
  __shared__ float sh[INBN ? KD : 1];
  __shared__ float red_s[OSUM ? 128 : 1];
  __shared__ float red_q[OSUM ? 128 : 1];
  const int tid = threadIdx.x;
  if (INBN) {
    for (int c = tid; c < KD; c += 256) {
      float mean = isum[c] * inv_cnt;
      float var = isq[c] * inv_cnt - mean * mean;
      float is_ = rsqrtf(var + 1e-5f);
      float scl = gamma[c] * is_;
      sc[c] = scl;
      sh[c] = beta[c] - mean * scl;
    }
  }
  if (OSUM && tid < 128) { red_s[tid] = 0.f; red_q[tid] = 0.f; }
  __syncthreads();
  const int wave = tid >> 6, lane = tid & 63;
  const int wm = wave >> 1, wn = wave & 1;
  const int r = lane & 15, g = lane >> 4;
  const size_t m0 = (size_t)blockIdx.x * 128 + wm * 64;
  const int n0 = blockIdx.y * 128 + wn * 64;

  f32x4 acc[4][4] = {};
  for (int ks = 0; ks < KD / 32; ks++) {
    const int kb = ks * 32 + g * 8;
    bf16x8 bh[4], bl[4];
    #pragma unroll
    for (int nf = 0; nf < 4; nf++) {
      bh[nf] = *(const bf16x8*)&Wh[(size_t)(n0 + nf * 16 + r) * KD + kb];
      bl[nf] = *(const bf16x8*)&Wl[(size_t)(n0 + nf * 16 + r) * KD + kb];
    }
    float s8[8], h8[8];
    if (INBN) {
      #pragma unroll
      for (int j = 0; j < 8; j++) { s8[j] = sc[kb + j]; h8[j] = sh[kb + j]; }
    }
    #pragma unroll
    for (int mf = 0; mf < 4; mf++) {
      const float* ap = &A[(m0 + mf * 16 + r) * KD + kb];
      float4 x0 = *(const float4*)ap;
      float4 x1 = *(const float4*)(ap + 4);
      float xv[8] = {x0.x, x0.y, x0.z, x0.w, x1.x, x1.y, x1.z, x1.w};
      bf16x8 ah, al;
      #pragma unroll
      for (int j = 0; j < 8; j++) {
        float x = xv[j];
        if (INBN) x = fmaxf(fmaf(x, s8[j], h8[j]), 0.f);
        short hh, ll;
        split2(x, hh, ll);
        ah[j] = hh;
        al[j] = ll;
      }
      #pragma unroll
      for (int nf = 0; nf < 4; nf++) {
        acc[mf][nf] = __builtin_amdgcn_mfma_f32_16x16x32_bf16(
            ah, bh[nf], acc[mf][nf], 0, 0, 0);
        acc[mf][nf] = __builtin_amdgcn_mfma_f32_16x16x32_bf16(
            al, bh[nf], acc[mf][nf], 0, 0, 0);
        acc[mf][nf] = __builtin_amdgcn_mfma_f32_16x16x32_bf16(
            ah, bl[nf], acc[mf][nf], 0, 0, 0);
      }
    }
  }
  float bv[4];
  if (HASBIAS) {
    #pragma unroll
    for (int nf = 0; nf < 4; nf++) bv[nf] = bias[n0 + nf * 16 + r];
  }
  float ps[4] = {0.f, 0.f, 0.f, 0.f}, pq[4] = {0.f, 0.f, 0.f, 0.f};
  #pragma unroll
  for (int mf = 0; mf < 4; mf++) {
    #pragma unroll
    for (int nf = 0; nf < 4; nf++) {
      #pragma unroll
      for (int j = 0; j < 4; j++) {
        float v = acc[mf][nf][j];
        if (HASBIAS) v += bv[nf];
        size_t row = m0 + mf * 16 + g * 4 + j;
        int col = n0 + nf * 16 + r;
        if (OSUM) { ps[nf] += v; pq[nf] += v * v; }
        outp[row * N + col] = v;
      }
    }
  }
  if (OSUM) {
    #pragma unroll
    for (int nf = 0; nf < 4; nf++) {
      #pragma unroll
      for (int off = 16; off < 64; off <<= 1) {
        ps[nf] += __shfl_xor(ps[nf], off, 64);
        pq[nf] += __shfl_xor(pq[nf], off, 64);
      }
    }
    if (lane < 16) {
      #pragma unroll
      for (int nf = 0; nf < 4; nf++) {
        int lcol = wn * 64 + nf * 16 + r;
        atomicAdd(&red_s[lcol], ps[nf]);
        atomicAdd(&red_q[lcol], pq[nf]);
      }
    }
    __syncthreads();
    if (tid < 128) {
      atomicAdd(&osum[blockIdx.y * 128 + tid], red_s[tid]);
      atomicAdd(&osq[blockIdx.y * 128 + tid], red_q[tid]);
    }
  }
}

// ---------------- f32 SIMD GEMM (conv3 only: N=325, + clip_in f32 emit) -----
template <int KD, bool INBN, bool HASBIAS, bool WCLIP>
__global__ __launch_bounds__(256) void gemm_f32(
    const float* __restrict__ A, int lda, const float* __restrict__ W, int N,
    const float* __restrict__ bias, const float* __restrict__ isum,
    const float* __restrict__ isq, float inv_cnt,
    const float* __restrict__ gamma, const float* __restrict__ beta,
    float* __restrict__ Cout, int ldc, float* __restrict__ clipf) {
  __shared__ float a_t[32][68];
  __shared__ float b_t[32][128];
  __shared__ float sc[INBN ? KD : 1];
  __shared__ float sh[INBN ? KD : 1];
  const int tid = threadIdx.x;
  const int m0 = blockIdx.x * 64;
  const int n0 = blockIdx.y * 128;
  if (INBN) {
    for (int c = tid; c < KD; c += 256) {
      float mean = isum[c] * inv_cnt;
      float var = isq[c] * inv_cnt - mean * mean;
      float is_ = rsqrtf(var + 1e-5f);
      float scl = gamma[c] * is_;
      sc[c] = scl;
      sh[c] = beta[c] - mean * scl;
    }
    __syncthreads();
  }
  float acc[4][8];
  #pragma unroll
  for (int i = 0; i < 4; i++)
    #pragma unroll
    for (int j = 0; j < 8; j++) acc[i][j] = 0.f;
  const int ty = tid >> 4, tx = tid & 15;
  for (int c0 = 0; c0 < KD; c0 += 32) {
    {
      const int lr = tid >> 2, lcs = tid & 3;
      #pragma unroll
      for (int i = 0; i < 8; i++) {
        int c = c0 + lcs + 4 * i;
        float v = A[(size_t)(m0 + lr) * lda + c];
        if (INBN) v = fmaxf(fmaf(v, sc[c], sh[c]), 0.f);
        a_t[lcs + 4 * i][lr] = v;
      }
    }
    {
      #pragma unroll
      for (int p = 0; p < 4; p++) {
        int cc = p * 8 + (tid >> 5);
        int nl = (tid & 31) * 4;
        #pragma unroll
        for (int u = 0; u < 4; u++) {
          int n = n0 + nl + u;
          b_t[cc][nl + u] = (n < N) ? W[(size_t)(c0 + cc) * N + n] : 0.f;
        }
      }
    }
    __syncthreads();
    #pragma unroll
    for (int kk = 0; kk < 32; kk++) {
      float4 av = *(const float4*)&a_t[kk][ty * 4];
      float4 b0 = *(const float4*)&b_t[kk][tx * 4];
      float4 b1 = *(const float4*)&b_t[kk][tx * 4 + 64];
      float ap[4] = {av.x, av.y, av.z, av.w};
      float bq0[4] = {b0.x, b0.y, b0.z, b0.w};
      float bq1[4] = {b1.x, b1.y, b1.z, b1.w};
      #pragma unroll
      for (int i = 0; i < 4; i++) {
        #pragma unroll
        for (int u = 0; u < 4; u++) {
          acc[i][u] = fmaf(ap[i], bq0[u], acc[i][u]);
          acc[i][4 + u] = fmaf(ap[i], bq1[u], acc[i][4 + u]);
        }
      }
    }
    __syncthreads();
  }
  #pragma unroll
  for (int i = 0; i < 4; i++) {
    size_t m = (size_t)(m0 + ty * 4 + i);
    #pragma unroll
    for (int gq = 0; gq < 2; gq++) {
      #pragma unroll
      for (int u = 0; u < 4; u++) {
        int n = n0 + gq * 64 + tx * 4 + u;
        if (n < N) {
          float v = acc[i][gq * 4 + u];
          if (HASBIAS) v += bias[n];
          Cout[m * ldc + n] = v;
          if (WCLIP && n >= 69) clipf[m * 256 + (n - 69)] = v;
        }
      }
    }
  }
}

// ---------------- gather layer-1 (f32 out + bn0 sums) ----------------
__global__ __launch_bounds__(256) void gather_l1(
    const float* __restrict__ F1, const int* __restrict__ idxl,
    const float* __restrict__ gx, const float* __restrict__ g_w0,
    float* __restrict__ L1, float* __restrict__ s0, float* __restrict__ q0) {
  int col = threadIdx.x & 127, half = threadIdx.x >> 7;
  int row0 = blockIdx.x * 64 + half * 32;
  float w0 = g_w0[col], w1 = g_w0[128 + col], w2 = g_w0[256 + col];
  __shared__ float rs[128], rq[128];
  if (threadIdx.x < 128) { rs[threadIdx.x] = 0.f; rq[threadIdx.x] = 0.f; }
  __syncthreads();
  float s = 0.f, q = 0.f;
  for (int rr = 0; rr < 32; rr++) {
    int row = row0 + rr;
    int b = row >> 13;
    int idx = idxl[row];
    float g0 = gx[(size_t)row * 3], g1 = gx[(size_t)row * 3 + 1],
          g2 = gx[(size_t)row * 3 + 2];
    float v = F1[((size_t)(b * Kk + idx)) * 128 + col] + g0 * w0 + g1 * w1 +
              g2 * w2;
    L1[(size_t)row * 128 + col] = v;
    s += v;
    q += v * v;
  }
  atomicAdd(&rs[col], s);
  atomicAdd(&rq[col], q);
  __syncthreads();
  if (threadIdx.x < 128) {
    atomicAdd(&s0[threadIdx.x], rs[threadIdx.x]);
    atomicAdd(&q0[threadIdx.x], rq[threadIdx.x]);
  }
}

// ---------------- bn + relu + max over S ----------------
__global__ __launch_bounds__(256) void maxpool_bn(
    const float* __restrict__ L3, const float* __restrict__ s2,
    const float* __restrict__ q2, const float* __restrict__ gam,
    const float* __restrict__ bet, float* __restrict__ feat) {
  int col = threadIdx.x & 127, half = threadIdx.x >> 7;
  int bq = blockIdx.x * 2 + half;
  float mean = s2[col] * (1.f / 131072.f);
  float var = q2[col] * (1.f / 131072.f) - mean * mean;
  float is_ = rsqrtf(var + 1e-5f);
  float scl = gam[col] * is_, shf = bet[col] - mean * scl;
  float m = -1e30f;
  #pragma unroll
  for (int s_ = 0; s_ < Ss; s_++) {
    float v = L3[((size_t)bq * Ss + s_) * 128 + col];
    v = fmaxf(fmaf(v, scl, shf), 0.f);
    m = fmaxf(m, v);
  }
  feat[(size_t)bq * 128 + col] = m;
}

// ---------------- final: q-norm, logits, coalesced transpose-assemble -------
__global__ __launch_bounds__(512) void final2(const float* __restrict__ net,
                                              const float* __restrict__ qbuf,
                                              const float* __restrict__ tn,
                                              float* __restrict__ out) {
  __shared__ float tile[79][65];
  const int blk = blockIdx.x;
  const int tid = threadIdx.x;
  const int r = tid >> 3, oct = tid & 7;
  const int row = blk * 64 + r;
  const int b = (blk * 64) >> 9, p0 = (blk * 64) & 511;

  const float* qr = qbuf + (size_t)row * 512 + oct * 64;
  float4 q4[16];
  #pragma unroll
  for (int i = 0; i < 16; i++) q4[i] = *(const float4*)(qr + 4 * i);
  float ss = 0.f;
  float dot[10];
  #pragma unroll
  for (int t = 0; t < 10; t++) dot[t] = 0.f;
  #pragma unroll
  for (int i = 0; i < 16; i++) {
    float4 a = q4[i];
    ss += a.x * a.x + a.y * a.y + a.z * a.z + a.w * a.w;
    #pragma unroll
    for (int t = 0; t < 10; t++) {
      float4 b4 = *(const float4*)(tn + (size_t)t * 512 + oct * 64 + i * 4);
      dot[t] += a.x * b4.x + a.y * b4.y + a.z * b4.z + a.w * b4.w;
    }
  }
  #pragma unroll
  for (int off = 1; off < 8; off <<= 1) {
    ss += __shfl_xor(ss, off, 8);
    #pragma unroll
    for (int t = 0; t < 10; t++) dot[t] += __shfl_xor(dot[t], off, 8);
  }
  if (oct == 0) {
    float inv = rsqrtf(ss) * (1.f / 0.07f);
    #pragma unroll
    for (int t = 0; t < 10; t++) tile[69 + t][r] = dot[t] * inv;
  }
  for (int idx = tid; idx < 64 * 69; idx += 512) {
    int r2 = idx / 69, ch = idx - 69 * r2;
    tile[ch][r2] = net[(size_t)(blk * 64 + r2) * 325 + ch];
  }
  __syncthreads();
  for (int idx = tid; idx < 79 * 64; idx += 512) {
    int ch = idx >> 6, rr = idx & 63;
    out[((size_t)b * 79 + ch) * 512 + p0 + rr] = tile[ch][rr];
  }
}

extern "C" void kernel_launch(void* const* d_in, const int* in_sizes, int n_in,
                              void* d_out, int out_size, void* d_ws,
                              size_t ws_size, hipStream_t stream) {
  const float* xyz = (const float*)d_in[0];
  const float* features = (const float*)d_in[1];
  const float* text = (const float*)d_in[2];
  const float* g_w0 = (const float*)d_in[3];
  const float* g_w1 = (const float*)d_in[4];
  const float* g_w2 = (const float*)d_in[5];
  const float* g_gam0 = (const float*)d_in[6];
  const float* g_bet0 = (const float*)d_in[7];
  const float* g_gam1 = (const float*)d_in[8];
  const float* g_bet1 = (const float*)d_in[9];
  const float* g_gam2 = (const float*)d_in[10];
  const float* g_bet2 = (const float*)d_in[11];
  const float* conv1_w = (const float*)d_in[12];
  const float* conv1_b = (const float*)d_in[13];
  const float* bn1_g = (const float*)d_in[14];
  const float* bn1_b = (const float*)d_in[15];
  const float* conv2_w = (const float*)d_in[16];
  const float* conv2_b = (const float*)d_in[17];
  const float* bn2_g = (const float*)d_in[18];
  const float* bn2_b = (const float*)d_in[19];
  const float* conv3_w = (const float*)d_in[20];
  const float* conv3_b = (const float*)d_in[21];
  const float* h_w0 = (const float*)d_in[22];
  const float* h_b0 = (const float*)d_in[23];
  const float* h_g0 = (const float*)d_in[24];
  const float* h_be0 = (const float*)d_in[25];
  const float* h_w1 = (const float*)d_in[26];
  const float* h_b1 = (const float*)d_in[27];
  const float* h_g1 = (const float*)d_in[28];
  const float* h_be1 = (const float*)d_in[29];
  const float* h_w2 = (const float*)d_in[30];
  const float* h_b2 = (const float*)d_in[31];
  float* out = (float*)d_out;
  char* ws = (char*)d_ws;

  float* tn = (float*)(ws + OFF_TNORM);
  float* sums = (float*)(ws + OFF_SUMS);
  int* inds = (int*)(ws + OFF_INDS);
  int* idxl = (int*)(ws + OFF_IDXL);
  float* gx = (float*)(ws + OFF_GX);
  float* F1 = (float*)(ws + OFF_F1);
  float* BIGA = (float*)(ws + OFF_BIGA);
  float* BIGB = (float*)(ws + OFF_BIGB);
  float* FEAT = (float*)(ws + OFF_BIGB);
  float* C1F = (float*)(ws + OFF_BIGB + 4194304);
  float* C2F = (float*)(ws + OFF_BIGB + 8388608);
  float* CLIPF = (float*)(ws + OFF_BIGB + 12582912);
  float* H0F = (float*)(ws + OFF_BIGA);
  float* H1F = (float*)(ws + OFF_BIGA + 16777216);
  float* QF = (float*)(ws + OFF_BIGA + 33554432);
  float* net = (float*)(ws + OFF_NET);
  unsigned short* WTH = (unsigned short*)(ws + OFF_WTH);
  unsigned short* WTL = (unsigned short*)(ws + OFF_WTL);

  hipMemsetAsync(sums, 0, 16384, stream);
  fused_pre<<<625, 256, 0, stream>>>(xyz, inds, features, g_w0, F1, text, tn,
                                     g_w1, g_w2, conv1_w, conv2_w, h_w0, h_w1,
                                     h_w2, WTH, WTL);
  neigh_k<<<2048, 256, 0, stream>>>(xyz, inds, idxl, gx);
  gather_l1<<<2048, 256, 0, stream>>>(F1, idxl, gx, g_w0, BIGA, sums + SB0S,
                                      sums + SB0Q);
  // L2 = relu(bn0(L1)) @ g_w1   (131072 x 128 x 128, split-MFMA)
  gemm_mfma<128, true, false, true><<<dim3(1024, 1), 256, 0, stream>>>(
      BIGA, WTH + WT_GW1, WTL + WT_GW1, nullptr, sums + SB0S, sums + SB0Q,
      1.f / 131072.f, g_gam0, g_bet0, BIGB, 128, sums + SB1S, sums + SB1Q);
  // L3 = relu(bn1(L2)) @ g_w2
  gemm_mfma<128, true, false, true><<<dim3(1024, 1), 256, 0, stream>>>(
      BIGB, WTH + WT_GW2, WTL + WT_GW2, nullptr, sums + SB1S, sums + SB1Q,
      1.f / 131072.f, g_gam1, g_bet1, BIGA, 128, sums + SB2S, sums + SB2Q);
  // feat = max_s relu(bn2(L3))
  maxpool_bn<<<4096, 256, 0, stream>>>(BIGA, sums + SB2S, sums + SB2Q, g_gam2,
                                       g_bet2, FEAT);
  // c1 = feat @ conv1_w + b
  gemm_mfma<128, false, true, true><<<dim3(64, 1), 256, 0, stream>>>(
      FEAT, WTH + WT_C1, WTL + WT_C1, conv1_b, nullptr, nullptr, 0.f, nullptr,
      nullptr, C1F, 128, sums + SC1S, sums + SC1Q);
  // c2 = relu(bn(c1)) @ conv2_w + b
  gemm_mfma<128, true, true, true><<<dim3(64, 1), 256, 0, stream>>>(
      C1F, WTH + WT_C2, WTL + WT_C2, conv2_b, sums + SC1S, sums + SC1Q,
      1.f / 8192.f, bn1_g, bn1_b, C2F, 128, sums + SC2S, sums + SC2Q);
  // net = relu(bn(c2)) @ conv3_w + b   (N=325, f32 SIMD; emits clip_in f32)
  gemm_f32<128, true, true, true><<<dim3(128, 3), 256, 0, stream>>>(
      C2F, 128, conv3_w, 325, conv3_b, sums + SC2S, sums + SC2Q, 1.f / 8192.f,
      bn2_g, bn2_b, net, 325, CLIPF);
  // h0 = clip_in @ h_w0 + b
  gemm_mfma<256, false, true, true><<<dim3(64, 4), 256, 0, stream>>>(
      CLIPF, WTH + WT_H0, WTL + WT_H0, h_b0, nullptr, nullptr, 0.f, nullptr,
      nullptr, H0F, 512, sums + SH0S, sums + SH0Q);
  // h1 = relu(bn(h0)) @ h_w1 + b
  gemm_mfma<512, true, true, true><<<dim3(64, 4), 256, 0, stream>>>(
      H0F, WTH + WT_H1, WTL + WT_H1, h_b1, sums + SH0S, sums + SH0Q,
      1.f / 8192.f, h_g0, h_be0, H1F, 512, sums + SH1S, sums + SH1Q);
  // q = relu(bn(h1)) @ h_w2 + b
  gemm_mfma<512, true, true, false><<<dim3(64, 4), 256, 0, stream>>>(
      H1F, WTH + WT_H2, WTL + WT_H2, h_b2, sums + SH1S, sums + SH1Q,
      1.f / 8192.f, h_g1, h_be1, QF, 512, nullptr, nullptr);
  final2<<<128, 512, 0, stream>>>(net, QF, tn, out);
}

// Round 8
// 784.475 us; speedup vs baseline: 2.4020x; 1.0820x over previous
//
#include <hip/hip_runtime.h>
#include <hip/hip_bf16.h>
#include <cstdint>
#include <cstddef>

#define Bb 16
#define Kk 2048
#define Pp 512
#define Ss 16
#define Cc 256

typedef __attribute__((ext_vector_type(8))) short bf16x8;
typedef __attribute__((ext_vector_type(4))) float f32x4;
typedef float v2f __attribute__((ext_vector_type(2)));

__device__ __forceinline__ unsigned short f2bf(float x) {  // RNE
  unsigned u = __float_as_uint(x);
  u = (u + 0x7FFF + ((u >> 16) & 1)) >> 16;
  return (unsigned short)u;
}
__device__ __forceinline__ float bf2f(unsigned short s) {
  return __uint_as_float((unsigned)s << 16);
}
// truncation split: x ~= hi + lo with |x-hi-lo| <= 2^-16 |x|
__device__ __forceinline__ void split2(float x, short& h, short& l) {
  unsigned u = __float_as_uint(x);
  h = (short)(u >> 16);
  float r = x - __uint_as_float(u & 0xFFFF0000u);
  l = (short)(__float_as_uint(r) >> 16);
}

// ---------------- workspace layout (bytes) ----------------
static constexpr size_t OFF_TNORM = 0;                          // 20480
static constexpr size_t OFF_SUMS  = 20480;                      // 16384
static constexpr size_t OFF_INDS  = 36864;                      // 32768
static constexpr size_t OFF_IDXL  = 69632;                      // 524288
static constexpr size_t OFF_GX    = 593920;                     // 1572864
static constexpr size_t OFF_F1    = 2166784;                    // 16777216 f32
static constexpr size_t OFF_BIGA  = 18944000;                   // 67108864 f32
static constexpr size_t OFF_BIGB  = 86052864;                   // 67108864 f32
static constexpr size_t OFF_NET   = 153161728;                  // 2260992 f32 (8192x69)
static constexpr size_t OFF_WTH   = 155422720;                  // 1540096 bf16
static constexpr size_t OFF_WTL   = 156962816;                  // 1540096 bf16
// BIGA aliases (L1 dead after L2): FEAT +0 (4MB), C1F +4M, C2F +8M, CLIPF +12M
// BIGB aliases (dead after L3):    H0F +0, H1F +16M, QF +32M

// Wt element offsets ([N][K] row-major bf16)
#define WT_GW1 0
#define WT_GW2 16384
#define WT_C1  32768
#define WT_C2  49152
#define WT_H0  65536
#define WT_H1  196608
#define WT_H2  458752
#define WT_C3  720896   // 384x128 (N padded, rows >=325 zero)

// sum-slot float offsets inside OFF_SUMS
#define SB0S 0
#define SB0Q 128
#define SB1S 256
#define SB1Q 384
#define SB2S 512
#define SB2Q 640
#define SC1S 768
#define SC1Q 896
#define SC2S 1024
#define SC2Q 1152
#define SH0S 1280
#define SH0Q 1792
#define SH1S 2304
#define SH1Q 2816

template <int CTRL>
__device__ __forceinline__ float fmax_dpp(float v) {
  int o = __builtin_amdgcn_update_dpp(0, __float_as_int(v), CTRL, 0xF, 0xF, true);
  return fmaxf(v, __int_as_float(o));
}

// fused: fps (0..15) | F1 gemm (16..527) | tnorm (528) | wprep (529..628)
__global__ __launch_bounds__(256, 1) void fused_pre(
    const float* __restrict__ xyz, int* __restrict__ inds,
    const float* __restrict__ features, const float* __restrict__ g_w0,
    float* __restrict__ F1, const float* __restrict__ text,
    float* __restrict__ tn, const float* __restrict__ g_w1,
    const float* __restrict__ g_w2, const float* __restrict__ conv1_w,
    const float* __restrict__ conv2_w, const float* __restrict__ conv3_w,
    const float* __restrict__ h_w0, const float* __restrict__ h_w1,
    const float* __restrict__ h_w2, unsigned short* __restrict__ wth,
    unsigned short* __restrict__ wtl) {
  __shared__ __align__(16) float smem[8208];
  const int tid = threadIdx.x;

  if (blockIdx.x < 16) {
    // ===== FPS: 4 waves, thread-major k = tid*8+j, packed-f32 distances ====
    #pragma clang fp contract(off)
    const int b = blockIdx.x;
    float4* pt4 = (float4*)smem;
    unsigned long long (*redw)[4] = (unsigned long long(*)[4])(smem + 8192);
    const float* base = xyz + (size_t)b * Kk * 3;
    for (int i = tid; i < Kk; i += 256) {
      pt4[i] = make_float4(base[3 * i], base[3 * i + 1], base[3 * i + 2], 0.f);
    }
    if (tid == 0) inds[b * Pp] = 0;
    v2f PX[4], PY[4], PZ[4], DM[4];
    {
      const float* pb = base + tid * 24;
      float4 f0 = *(const float4*)(pb + 0);
      float4 f1 = *(const float4*)(pb + 4);
      float4 f2 = *(const float4*)(pb + 8);
      float4 f3 = *(const float4*)(pb + 12);
      float4 f4 = *(const float4*)(pb + 16);
      float4 f5 = *(const float4*)(pb + 20);
      // points j: (x,y,z) = pb[3j..]; pair p = (j=2p, j=2p+1)
      PX[0] = (v2f){f0.x, f0.w}; PY[0] = (v2f){f0.y, f1.x}; PZ[0] = (v2f){f0.z, f1.y};
      PX[1] = (v2f){f1.z, f2.y}; PY[1] = (v2f){f1.w, f2.z}; PZ[1] = (v2f){f2.x, f2.w};
      PX[2] = (v2f){f3.x, f3.w}; PY[2] = (v2f){f3.y, f4.x}; PZ[2] = (v2f){f3.z, f4.y};
      PX[3] = (v2f){f4.z, f5.y}; PY[3] = (v2f){f4.w, f5.z}; PZ[3] = (v2f){f5.x, f5.w};
      #pragma unroll
      for (int p = 0; p < 4; p++) DM[p] = (v2f){1e10f, 1e10f};
    }
    __syncthreads();
    const int lane = tid & 63, wid = tid >> 6;
    int last = 0;
    for (int it = 1; it < Pp; ++it) {
      float4 L = pt4[last];
      v2f vlx = {L.x, L.x}, vly = {L.y, L.y}, vlz = {L.z, L.z};
      float pf[4];
      int pk_[4];
      #pragma unroll
      for (int p = 0; p < 4; p++) {
        v2f dx = PX[p] - vlx, dy = PY[p] - vly, dz = PZ[p] - vlz;
        v2f d = (dx * dx + dy * dy) + dz * dz;  // contract off: exact mul/add
        v2f m2 = __builtin_elementwise_min(DM[p], d);
        DM[p] = m2;
        bool t = m2.y > m2.x;              // strict >: prefer lower index
        pf[p] = t ? m2.y : m2.x;
        pk_[p] = 2 * p + (t ? 1 : 0);
      }
      // tree over 4 pairs, prefer lower p
      bool t01 = pf[1] > pf[0];
      float f01 = t01 ? pf[1] : pf[0];
      int k01 = t01 ? pk_[1] : pk_[0];
      bool t23 = pf[3] > pf[2];
      float f23 = t23 ? pf[3] : pf[2];
      int k23 = t23 ? pk_[3] : pk_[2];
      bool tt = f23 > f01;
      float bf = tt ? f23 : f01;
      int bj = tt ? k23 : k01;
      // 64-lane max: xor1,2,7,15 (row reduce) + bcast15 + bcast31 -> lane 63
      float g = bf;
      g = fmax_dpp<0xB1>(g);   // quad_perm xor 1
      g = fmax_dpp<0x4E>(g);   // quad_perm xor 2
      g = fmax_dpp<0x141>(g);  // row_half_mirror (xor 7)
      g = fmax_dpp<0x140>(g);  // row_mirror (xor 15)
      g = fmax_dpp<0x142>(g);  // row_bcast15 (d >= 0, bound_ctrl0 safe)
      g = fmax_dpp<0x143>(g);  // row_bcast31 -> lane63 = full max
      float gs = __uint_as_float(
          (unsigned)__builtin_amdgcn_readlane(__float_as_int(g), 63));
      unsigned long long msk = __ballot(bf == gs);
      int src = __builtin_ctzll(msk);  // lowest lane = lowest k
      int kk = (tid << 3) | bj;
      int kwin = __builtin_amdgcn_readlane(kk, src);
      if (lane == 0)
        redw[it & 1][wid] = ((unsigned long long)__float_as_uint(gs) << 32) |
                            (unsigned)(~(unsigned)kwin);
      __syncthreads();
      unsigned long long q0 = redw[it & 1][0], q1 = redw[it & 1][1];
      unsigned long long q2 = redw[it & 1][2], q3 = redw[it & 1][3];
      unsigned long long m0 = q0 > q1 ? q0 : q1;
      unsigned long long m1 = q2 > q3 ? q2 : q3;
      unsigned long long mm = m0 > m1 ? m0 : m1;
      last = (int)(~(unsigned)mm);
      if (tid == 0) inds[b * Pp + it] = last;
    }
  } else if (blockIdx.x == 528) {
    // ===== text-feature normalization ======================================
    int w = tid >> 6, lane = tid & 63;
    for (int r = w; r < 10; r += 4) {
      const float* rw = text + (size_t)r * 512;
      float v[8];
      float ss = 0.f;
      #pragma unroll
      for (int u = 0; u < 8; u++) { v[u] = rw[lane + 64 * u]; ss += v[u] * v[u]; }
      #pragma unroll
      for (int off = 32; off; off >>= 1) ss += __shfl_xor(ss, off, 64);
      float nrm = sqrtf(ss);
      #pragma unroll
      for (int u = 0; u < 8; u++)
        tn[(size_t)r * 512 + lane + 64 * u] = v[u] / nrm;
    }
  } else if (blockIdx.x >= 529) {
    // ===== weight transpose + RNE bf16 split (parallel, 100 blocks) =======
    int wb = blockIdx.x - 529;
    const float* W;
    int K, N, NS, nblk, pidx;  // NS = source N (unpadded)
    unsigned short *dh, *dl;
    if (wb < 4)       { W = g_w1;    K = 128; N = 128; NS = 128; dh = wth + WT_GW1; dl = wtl + WT_GW1; nblk = 4;  pidx = wb; }
    else if (wb < 8)  { W = g_w2;    K = 128; N = 128; NS = 128; dh = wth + WT_GW2; dl = wtl + WT_GW2; nblk = 4;  pidx = wb - 4; }
    else if (wb < 12) { W = conv1_w; K = 128; N = 128; NS = 128; dh = wth + WT_C1;  dl = wtl + WT_C1;  nblk = 4;  pidx = wb - 8; }
    else if (wb < 16) { W = conv2_w; K = 128; N = 128; NS = 128; dh = wth + WT_C2;  dl = wtl + WT_C2;  nblk = 4;  pidx = wb - 12; }
    else if (wb < 32) { W = h_w0;    K = 256; N = 512; NS = 512; dh = wth + WT_H0;  dl = wtl + WT_H0;  nblk = 16; pidx = wb - 16; }
    else if (wb < 64) { W = h_w1;    K = 512; N = 512; NS = 512; dh = wth + WT_H1;  dl = wtl + WT_H1;  nblk = 32; pidx = wb - 32; }
    else if (wb < 96) { W = h_w2;    K = 512; N = 512; NS = 512; dh = wth + WT_H2;  dl = wtl + WT_H2;  nblk = 32; pidx = wb - 64; }
    else              { W = conv3_w; K = 128; N = 384; NS = 325; dh = wth + WT_C3;  dl = wtl + WT_C3;  nblk = 4;  pidx = wb - 96; }
    for (int idx = pidx * 256 + tid; idx < K * N; idx += nblk * 256) {
      int k = idx / N, n = idx - k * N;
      float w = (n < NS) ? W[k * NS + n] : 0.f;
      unsigned short hi = f2bf(w);
      unsigned short lo = f2bf(w - bf2f(hi));
      dh[n * K + k] = hi;
      dl[n * K + k] = lo;
    }
  } else {
    // ===== F1 = feats_kc @ g_w0[3:,:]  (32768 x 256 x 128) ================
    float (*a_t)[68] = (float(*)[68])smem;
    float (*b_t)[128] = (float(*)[128])(smem + 32 * 68);
    const float* W = g_w0 + 3 * 128;
    const int m0 = (blockIdx.x - 16) * 64;
    float acc[4][8];
    #pragma unroll
    for (int i = 0; i < 4; i++)
      #pragma unroll
      for (int j = 0; j < 8; j++) acc[i][j] = 0.f;
    const int ty = tid >> 4, tx = tid & 15;
    const int lr = tid & 63, wv = tid >> 6;
    const int bb = m0 >> 11, k0 = m0 & 2047;
    const float* fb = features + (size_t)bb * (Cc * Kk);
    for (int c0 = 0; c0 < 256; c0 += 32) {
      #pragma unroll
      for (int i = 0; i < 8; i++) {
        int c = c0 + wv + 4 * i;
        a_t[wv + 4 * i][lr] = fb[(size_t)c * Kk + k0 + lr];
      }
      #pragma unroll
      for (int p = 0; p < 4; p++) {
        int cc = p * 8 + (tid >> 5);
        int nl = (tid & 31) * 4;
        *(float4*)&b_t[cc][nl] = *(const float4*)&W[(size_t)(c0 + cc) * 128 + nl];
      }
      __syncthreads();
      #pragma unroll
      for (int kk = 0; kk < 32; kk++) {
        float4 av = *(const float4*)&a_t[kk][ty * 4];
        float4 b0 = *(const float4*)&b_t[kk][tx * 4];
        float4 b1 = *(const float4*)&b_t[kk][tx * 4 + 64];
        float ap[4] = {av.x, av.y, av.z, av.w};
        float bq0[4] = {b0.x, b0.y, b0.z, b0.w};
        float bq1[4] = {b1.x, b1.y, b1.z, b1.w};
        #pragma unroll
        for (int i = 0; i < 4; i++) {
          #pragma unroll
          for (int u = 0; u < 4; u++) {
            acc[i][u] = fmaf(ap[i], bq0[u], acc[i][u]);
            acc[i][4 + u] = fmaf(ap[i], bq1[u], acc[i][4 + u]);
          }
        }
      }
      __syncthreads();
    }
    #pragma unroll
    for (int i = 0; i < 4; i++) {
      size_t mrow = (size_t)(m0 + ty * 4 + i);
      #pragma unroll
      for (int gq = 0; gq < 2; gq++) {
        float4 v4 = make_float4(acc[i][gq * 4], acc[i][gq * 4 + 1],
                                acc[i][gq * 4 + 2], acc[i][gq * 4 + 3]);
        *(float4*)&F1[mrow * 128 + gq * 64 + tx * 4] = v4;
      }
    }
  }
}

// ---------------- neighbor selection ----------------
__global__ __launch_bounds__(256) void neigh_k(const float* __restrict__ xyz,
                                               const int* __restrict__ inds,
                                               int* __restrict__ idxl,
                                               float* __restrict__ gx) {
  int widx = blockIdx.x * 4 + (threadIdx.x >> 6);
  int lane = threadIdx.x & 63;
  int b = widx >> 9;
  int q = inds[widx];
  const float* base = xyz + (size_t)b * Kk * 3;
  float qx = base[3 * q], qy = base[3 * q + 1], qz = base[3 * q + 2];
  int cnt = 0;
  int myk = 0;
  for (int ch = 0; ch < 32 && cnt < Ss; ch++) {
    int k = ch * 64 + lane;
    float dx = base[3 * k] - qx;
    float dy = base[3 * k + 1] - qy;
    float dz = base[3 * k + 2] - qz;
    float d2 = __fadd_rn(__fadd_rn(__fmul_rn(dx, dx), __fmul_rn(dy, dy)),
                         __fmul_rn(dz, dz));
    unsigned long long m = __ballot(d2 < 0.09f);
    while (m && cnt < Ss) {
      int t = __builtin_ctzll(m);
      if (lane == cnt) myk = ch * 64 + t;
      cnt++;
      m &= m - 1;
    }
  }
  int first = __shfl(myk, 0, 64);
  if (lane < Ss) {
    int kk = (lane < cnt) ? myk : first;
    size_t o = (size_t)widx * Ss + lane;
    idxl[o] = kk;
    gx[o * 3 + 0] = (base[3 * kk] - qx) / 0.3f;
    gx[o * 3 + 1] = (base[3 * kk + 1] - qy) / 0.3f;
    gx[o * 3 + 2] = (base[3 * kk + 2] - qz) / 0.3f;
  }
}

// ------- split-bf16 MFMA GEMM: out = act_in(A) @ (Wh+Wl)^T (+bias) ---------
// OMAX: emit per-16-row-group max (feat) instead of full output (+stats).
// WCLIP: N-padded weights; cols<69 -> net (stride 69), 69..nout-1 -> clipf.
template <int KD, bool INBN, bool HASBIAS, bool OSUM, bool OMAX, bool WCLIP>
__global__ __launch_bounds__(256, 2) void gemm_mfma(
    const float* __restrict__ A, const unsigned short* __restrict__ Wh,
    const unsigned short* __restrict__ Wl, const float* __restrict__ bias,
    const float* __restrict__ isum, const float* __restrict__ isq,
    float inv_cnt, const float* __restrict__ gamma,
    const float* __restrict__ beta, float* __restrict__ outp, int N, int nout,
    float* __restrict__ clipf, float* __restrict__ osum,
    float* __restrict__ osq) {
  __shared__ float sc[INBN ? KD : 1];
  __shared__ float sh[INBN ? KD : 1];
  __shared__ float red_s[OSUM ? 128 : 1];
  __shared__ float red_q[OSUM ? 128 : 1];
  const int tid = threadIdx.x;
  if (INBN) {
    for (int c = tid; c < KD; c += 256) {
      float mean = isum[c] * inv_cnt;
      float var = isq[c] * inv_cnt - mean * mean;
      float is_ = rsqrtf(var + 1e-5f);
      float scl = gamma[c] * is_;
      sc[c] = scl;
      sh[c] = beta[c] - mean * scl;
    }
  }
  if (OSUM && tid < 128) { red_s[tid] = 0.f; red_q[tid] = 0.f; }
  __syncthreads();
  const int wave = tid >> 6, lane = tid & 63;
  const int wm = wave >> 1, wn = wave & 1;
  const int r = lane & 15, g = lane >> 4;
  const size_t m0 = (size_t)blockIdx.x * 128 + wm * 64;
  const int n0 = blockIdx.y * 128 + wn * 64;

  f32x4 acc[4][4] = {};
  for (int ks = 0; ks < KD / 32; ks++) {
    const int kb = ks * 32 + g * 8;
    bf16x8 bh[4], bl[4];
    #pragma unroll
    for (int nf = 0; nf < 4; nf++) {
      bh[nf] = *(const bf16x8*)&Wh[(size_t)(n0 + nf * 16 + r) * KD + kb];
      bl[nf] = *(const bf16x8*)&Wl[(size_t)(n0 + nf * 16 + r) * KD + kb];
    }
    float s8[8], h8[8];
    if (INBN) {
      #pragma unroll
      for (int j = 0; j < 8; j++) { s8[j] = sc[kb + j]; h8[j] = sh[kb + j]; }
    }
    #pragma unroll
    for (int mf = 0; mf < 4; mf++) {
      const float* ap = &A[(m0 + mf * 16 + r) * KD + kb];
      float4 x0 = *(const float4*)ap;
      float4 x1 = *(const float4*)(ap + 4);
      float xv[8] = {x0.x, x0.y, x0.z, x0.w, x1.x, x1.y, x1.z, x1.w};
      bf16x8 ah, al;
      #pragma unroll
      for (int j = 0; j < 8; j++) {
        float x = xv[j];
        if (INBN) x = fmaxf(fmaf(x, s8[j], h8[j]), 0.f);
        short hh, ll;
        split2(x, hh, ll);
        ah[j] = hh;
        al[j] = ll;
      }
      #pragma unroll
      for (int nf = 0; nf < 4; nf++) {
        acc[mf][nf] = __builtin_amdgcn_mfma_f32_16x16x32_bf16(
            ah, bh[nf], acc[mf][nf], 0, 0, 0);
        acc[mf][nf] = __builtin_amdgcn_mfma_f32_16x16x32_bf16(
            al, bh[nf], acc[mf][nf], 0, 0, 0);
        acc[mf][nf] = __builtin_amdgcn_mfma_f32_16x16x32_bf16(
            ah, bl[nf], acc[mf][nf], 0, 0, 0);
      }
    }
  }
  float bv[4];
  if (HASBIAS) {
    #pragma unroll
    for (int nf = 0; nf < 4; nf++) {
      int col = n0 + nf * 16 + r;
      bv[nf] = (!WCLIP || col < nout) ? bias[col] : 0.f;
    }
  }
  float ps[4] = {0.f, 0.f, 0.f, 0.f}, pq[4] = {0.f, 0.f, 0.f, 0.f};
  #pragma unroll
  for (int mf = 0; mf < 4; mf++) {
    float mx[4];
    #pragma unroll
    for (int nf = 0; nf < 4; nf++) {
      float vmax = -1e30f;
      #pragma unroll
      for (int j = 0; j < 4; j++) {
        float v = acc[mf][nf][j];
        if (HASBIAS) v += bv[nf];
        size_t row = m0 + mf * 16 + g * 4 + j;
        int col = n0 + nf * 16 + r;
        if (OSUM) { ps[nf] += v; pq[nf] += v * v; }
        if (OMAX) {
          vmax = fmaxf(vmax, v);
        } else if (WCLIP) {
          if (col < 69) outp[row * 69 + col] = v;
          else if (col < nout) clipf[row * 256 + (col - 69)] = v;
        } else {
          outp[row * N + col] = v;
        }
      }
      mx[nf] = vmax;
    }
    if (OMAX) {
      #pragma unroll
      for (int nf = 0; nf < 4; nf++) {
        float m = mx[nf];
        m = fmaxf(m, __shfl_xor(m, 16, 64));
        m = fmaxf(m, __shfl_xor(m, 32, 64));
        if (g == 0) {
          size_t bq = (m0 >> 4) + mf;  // group of 16 rows
          outp[bq * 128 + n0 + nf * 16 + r] = m;
        }
      }
    }
  }
  if (OSUM) {
    #pragma unroll
    for (int nf = 0; nf < 4; nf++) {
      #pragma unroll
      for (int off = 16; off < 64; off <<= 1) {
        ps[nf] += __shfl_xor(ps[nf], off, 64);
        pq[nf] += __shfl_xor(pq[nf], off, 64);
      }
    }
    if (lane < 16) {
      #pragma unroll
      for (int nf = 0; nf < 4; nf++) {
        int lcol = wn * 64 + nf * 16 + r;
        atomicAdd(&red_s[lcol], ps[nf]);
        atomicAdd(&red_q[lcol], pq[nf]);
      }
    }
    __syncthreads();
    if (tid < 128) {
      atomicAdd(&osum[blockIdx.y * 128 + tid], red_s[tid]);
      atomicAdd(&osq[blockIdx.y * 128 + tid], red_q[tid]);
    }
  }
}

// ---------------- gather layer-1 (f32 out + bn0 sums) ----------------
__global__ __launch_bounds__(256) void gather_l1(
    const float* __restrict__ F1, const int* __restrict__ idxl,
    const float* __restrict__ gx, const float* __restrict__ g_w0,
    float* __restrict__ L1, float* __restrict__ s0, float* __restrict__ q0) {
  int col = threadIdx.x & 127, half = threadIdx.x >> 7;
  int row0 = blockIdx.x * 64 + half * 32;
  float w0 = g_w0[col], w1 = g_w0[128 + col], w2 = g_w0[256 + col];
  __shared__ float rs[128], rq[128];
  if (threadIdx.x < 128) { rs[threadIdx.x] = 0.f; rq[threadIdx.x] = 0.f; }
  __syncthreads();
  float s = 0.f, q = 0.f;
  for (int rr = 0; rr < 32; rr++) {
    int row = row0 + rr;
    int b = row >> 13;
    int idx = idxl[row];
    float g0 = gx[(size_t)row * 3], g1 = gx[(size_t)row * 3 + 1],
          g2 = gx[(size_t)row * 3 + 2];
    float v = F1[((size_t)(b * Kk + idx)) * 128 + col] + g0 * w0 + g1 * w1 +
              g2 * w2;
    L1[(size_t)row * 128 + col] = v;
    s += v;
    q += v * v;
  }
  atomicAdd(&rs[col], s);
  atomicAdd(&rq[col], q);
  __syncthreads();
  if (threadIdx.x < 128) {
    atomicAdd(&s0[threadIdx.x], rs[threadIdx.x]);
    atomicAdd(&q0[threadIdx.x], rq[threadIdx.x]);
  }
}

// ---------------- final: q-norm, logits, coalesced transpose-assemble -------
__global__ __launch_bounds__(512) void final2(const float* __restrict__ net,
                                              const float* __restrict__ qbuf,
                                              const float* __restrict__ tn,
                                              float* __restrict__ out) {
  __shared__ float tile[79][65];
  const int blk = blockIdx.x;
  const int tid = threadIdx.x;
  const int r = tid >> 3, oct = tid & 7;
  const int row = blk * 64 + r;
  const int b = (blk * 64) >> 9, p0 = (blk * 64) & 511;

  const float* qr = qbuf + (size_t)row * 512 + oct * 64;
  float4 q4[16];
  #pragma unroll
  for (int i = 0; i < 16; i++) q4[i] = *(const float4*)(qr + 4 * i);
  float ss = 0.f;
  float dot[10];
  #pragma unroll
  for (int t = 0; t < 10; t++) dot[t] = 0.f;
  #pragma unroll
  for (int i = 0; i < 16; i++) {
    float4 a = q4[i];
    ss += a.x * a.x + a.y * a.y + a.z * a.z + a.w * a.w;
    #pragma unroll
    for (int t = 0; t < 10; t++) {
      float4 b4 = *(const float4*)(tn + (size_t)t * 512 + oct * 64 + i * 4);
      dot[t] += a.x * b4.x + a.y * b4.y + a.z * b4.z + a.w * b4.w;
    }
  }
  #pragma unroll
  for (int off = 1; off < 8; off <<= 1) {
    ss += __shfl_xor(ss, off, 8);
    #pragma unroll
    for (int t = 0; t < 10; t++) dot[t] += __shfl_xor(dot[t], off, 8);
  }
  if (oct == 0) {
    float inv = rsqrtf(ss) * (1.f / 0.07f);
    #pragma unroll
    for (int t = 0; t < 10; t++) tile[69 + t][r] = dot[t] * inv;
  }
  for (int idx = tid; idx < 64 * 69; idx += 512) {
    int r2 = idx / 69, ch = idx - 69 * r2;
    tile[ch][r2] = net[(size_t)(blk * 64 + r2) * 69 + ch];
  }
  __syncthreads();
  for (int idx = tid; idx < 79 * 64; idx += 512) {
    int ch = idx >> 6, rr = idx & 63;
    out[((size_t)b * 79 + ch) * 512 + p0 + rr] = tile[ch][rr];
  }
}

extern "C" void kernel_launch(void* const* d_in, const int* in_sizes, int n_in,
                              void* d_out, int out_size, void* d_ws,
                              size_t ws_size, hipStream_t stream) {
  const float* xyz = (const float*)d_in[0];
  const float* features = (const float*)d_in[1];
  const float* text = (const float*)d_in[2];
  const float* g_w0 = (const float*)d_in[3];
  const float* g_w1 = (const float*)d_in[4];
  const float* g_w2 = (const float*)d_in[5];
  const float* g_gam0 = (const float*)d_in[6];
  const float* g_bet0 = (const float*)d_in[7];
  const float* g_gam1 = (const float*)d_in[8];
  const float* g_bet1 = (const float*)d_in[9];
  const float* g_gam2 = (const float*)d_in[10];
  const float* g_bet2 = (const float*)d_in[11];
  const float* conv1_w = (const float*)d_in[12];
  const float* conv1_b = (const float*)d_in[13];
  const float* bn1_g = (const float*)d_in[14];
  const float* bn1_b = (const float*)d_in[15];
  const float* conv2_w = (const float*)d_in[16];
  const float* conv2_b = (const float*)d_in[17];
  const float* bn2_g = (const float*)d_in[18];
  const float* bn2_b = (const float*)d_in[19];
  const float* conv3_w = (const float*)d_in[20];
  const float* conv3_b = (const float*)d_in[21];
  const float* h_w0 = (const float*)d_in[22];
  const float* h_b0 = (const float*)d_in[23];
  const float* h_g0 = (const float*)d_in[24];
  const float* h_be0 = (const float*)d_in[25];
  const float* h_w1 = (const float*)d_in[26];
  const float* h_b1 = (const float*)d_in[27];
  const float* h_g1 = (const float*)d_in[28];
  const float* h_be1 = (const float*)d_in[29];
  const float* h_w2 = (const float*)d_in[30];
  const float* h_b2 = (const float*)d_in[31];
  float* out = (float*)d_out;
  char* ws = (char*)d_ws;

  float* tn = (float*)(ws + OFF_TNORM);
  float* sums = (float*)(ws + OFF_SUMS);
  int* inds = (int*)(ws + OFF_INDS);
  int* idxl = (int*)(ws + OFF_IDXL);
  float* gx = (float*)(ws + OFF_GX);
  float* F1 = (float*)(ws + OFF_F1);
  float* BIGA = (float*)(ws + OFF_BIGA);
  float* BIGB = (float*)(ws + OFF_BIGB);
  float* FEAT = (float*)(ws + OFF_BIGA);
  float* C1F = (float*)(ws + OFF_BIGA + 4194304);
  float* C2F = (float*)(ws + OFF_BIGA + 8388608);
  float* CLIPF = (float*)(ws + OFF_BIGA + 12582912);
  float* H0F = (float*)(ws + OFF_BIGB);
  float* H1F = (float*)(ws + OFF_BIGB + 16777216);
  float* QF = (float*)(ws + OFF_BIGB + 33554432);
  float* net = (float*)(ws + OFF_NET);
  unsigned short* WTH = (unsigned short*)(ws + OFF_WTH);
  unsigned short* WTL = (unsigned short*)(ws + OFF_WTL);

  hipMemsetAsync(sums, 0, 16384, stream);
  fused_pre<<<629, 256, 0, stream>>>(xyz, inds, features, g_w0, F1, text, tn,
                                     g_w1, g_w2, conv1_w, conv2_w, conv3_w,
                                     h_w0, h_w1, h_w2, WTH, WTL);
  neigh_k<<<2048, 256, 0, stream>>>(xyz, inds, idxl, gx);
  gather_l1<<<2048, 256, 0, stream>>>(F1, idxl, gx, g_w0, BIGA, sums + SB0S,
                                      sums + SB0Q);
  // L2 = relu(bn0(L1)) @ g_w1   (131072 x 128 x 128)
  gemm_mfma<128, true, false, true, false, false>
      <<<dim3(1024, 1), 256, 0, stream>>>(
          BIGA, WTH + WT_GW1, WTL + WT_GW1, nullptr, sums + SB0S, sums + SB0Q,
          1.f / 131072.f, g_gam0, g_bet0, BIGB, 128, 128, nullptr,
          sums + SB1S, sums + SB1Q);
  // L3 = relu(bn1(L2)) @ g_w2, fused raw max over S=16 -> FEAT (+bn2 stats)
  gemm_mfma<128, true, false, true, true, false>
      <<<dim3(1024, 1), 256, 0, stream>>>(
          BIGB, WTH + WT_GW2, WTL + WT_GW2, nullptr, sums + SB1S, sums + SB1Q,
          1.f / 131072.f, g_gam1, g_bet1, FEAT, 128, 128, nullptr,
          sums + SB2S, sums + SB2Q);
  // c1 = relu(bn2(feat)) @ conv1_w + b   (bn2 moved here: exact, gamma2>0)
  gemm_mfma<128, true, true, true, false, false>
      <<<dim3(64, 1), 256, 0, stream>>>(
          FEAT, WTH + WT_C1, WTL + WT_C1, conv1_b, sums + SB2S, sums + SB2Q,
          1.f / 131072.f, g_gam2, g_bet2, C1F, 128, 128, nullptr, sums + SC1S,
          sums + SC1Q);
  // c2 = relu(bn(c1)) @ conv2_w + b
  gemm_mfma<128, true, true, true, false, false>
      <<<dim3(64, 1), 256, 0, stream>>>(
          C1F, WTH + WT_C2, WTL + WT_C2, conv2_b, sums + SC1S, sums + SC1Q,
          1.f / 8192.f, bn1_g, bn1_b, C2F, 128, 128, nullptr, sums + SC2S,
          sums + SC2Q);
  // net/clip = relu(bn(c2)) @ conv3_w + b  (MFMA, N padded 384, nout=325)
  gemm_mfma<128, true, true, false, false, true>
      <<<dim3(64, 3), 256, 0, stream>>>(
          C2F, WTH + WT_C3, WTL + WT_C3, conv3_b, sums + SC2S, sums + SC2Q,
          1.f / 8192.f, bn2_g, bn2_b, net, 384, 325, CLIPF, nullptr, nullptr);
  // h0 = clip_in @ h_w0 + b
  gemm_mfma<256, false, true, true, false, false>
      <<<dim3(64, 4), 256, 0, stream>>>(
          CLIPF, WTH + WT_H0, WTL + WT_H0, h_b0, nullptr, nullptr, 0.f,
          nullptr, nullptr, H0F, 512, 512, nullptr, sums + SH0S, sums + SH0Q);
  // h1 = relu(bn(h0)) @ h_w1 + b
  gemm_mfma<512, true, true, true, false, false>
      <<<dim3(64, 4), 256, 0, stream>>>(
          H0F, WTH + WT_H1, WTL + WT_H1, h_b1, sums + SH0S, sums + SH0Q,
          1.f / 8192.f, h_g0, h_be0, H1F, 512, 512, nullptr, sums + SH1S,
          sums + SH1Q);
  // q = relu(bn(h1)) @ h_w2 + b
  gemm_mfma<512, true, true, false, false, false>
      <<<dim3(64, 4), 256, 0, stream>>>(
          H1F, WTH + WT_H2, WTL + WT_H2, h_b2, sums + SH1S, sums + SH1Q,
          1.f / 8192.f, h_g1, h_be1, QF, 512, 512, nullptr, nullptr, nullptr);
  final2<<<128, 512, 0, stream>>>(net, QF, tn, out);
}

// Round 9
// 749.748 us; speedup vs baseline: 2.5132x; 1.0463x over previous
//
#include <hip/hip_runtime.h>
#include <hip/hip_bf16.h>
#include <cstdint>
#include <cstddef>

#define Bb 16
#define Kk 2048
#define Pp 512
#define Ss 16
#define Cc 256

typedef __attribute__((ext_vector_type(8))) short bf16x8;
typedef __attribute__((ext_vector_type(4))) float f32x4;
typedef float v2f __attribute__((ext_vector_type(2)));

__device__ __forceinline__ unsigned short f2bf(float x) {  // RNE
  unsigned u = __float_as_uint(x);
  u = (u + 0x7FFF + ((u >> 16) & 1)) >> 16;
  return (unsigned short)u;
}
__device__ __forceinline__ float bf2f(unsigned short s) {
  return __uint_as_float((unsigned)s << 16);
}
// truncation split: x ~= hi + lo with |x-hi-lo| <= 2^-16 |x|
__device__ __forceinline__ void split2(float x, short& h, short& l) {
  unsigned u = __float_as_uint(x);
  h = (short)(u >> 16);
  float r = x - __uint_as_float(u & 0xFFFF0000u);
  l = (short)(__float_as_uint(r) >> 16);
}

// ---------------- workspace layout (bytes) ----------------
static constexpr size_t OFF_TNORM = 0;                          // 20480
static constexpr size_t OFF_SUMS  = 20480;                      // 16384
static constexpr size_t OFF_INDS  = 36864;                      // 32768
static constexpr size_t OFF_IDXL  = 69632;                      // 524288
static constexpr size_t OFF_GX    = 593920;                     // 1572864
static constexpr size_t OFF_F1    = 2166784;                    // 16777216 f32
static constexpr size_t OFF_BIGA  = 18944000;                   // 67108864
static constexpr size_t OFF_BIGB  = 86052864;                   // 67108864
static constexpr size_t OFF_NET   = 153161728;                  // 2260992 f32 (8192x69)
static constexpr size_t OFF_WTH   = 155422720;                  // 1540096 bf16
static constexpr size_t OFF_WTL   = 156962816;                  // 1540096 bf16
// BIGA: L2OUT bf16 (0..33.5M, dead after L3); QF f32 (0..16.7M, from h2 on)
// BIGB: FEAT +0 (4M) | C1F +4M | C2F +8M | CLIPF +12M (8M) | H0F +20M (16M)
//       | H1F +36M (16M)

// Wt element offsets ([N][K] row-major bf16)
#define WT_GW1 0
#define WT_GW2 16384
#define WT_C1  32768
#define WT_C2  49152
#define WT_H0  65536
#define WT_H1  196608
#define WT_H2  458752
#define WT_C3  720896   // 384x128 (N padded, rows >=325 zero)

// sum-slot float offsets inside OFF_SUMS
#define SB0S 0
#define SB0Q 128
#define SB1S 256
#define SB1Q 384
#define SB2S 512
#define SB2Q 640
#define SC1S 768
#define SC1Q 896
#define SC2S 1024
#define SC2Q 1152
#define SH0S 1280
#define SH0Q 1792
#define SH1S 2304
#define SH1Q 2816

template <int CTRL>
__device__ __forceinline__ float fmax_dpp(float v) {
  int o = __builtin_amdgcn_update_dpp(0, __float_as_int(v), CTRL, 0xF, 0xF, true);
  return fmaxf(v, __int_as_float(o));
}

// fused: fps (0..15) | F1 gemm (16..527) | tnorm (528) | wprep (529..628)
__global__ __launch_bounds__(256, 1) void fused_pre(
    const float* __restrict__ xyz, int* __restrict__ inds,
    const float* __restrict__ features, const float* __restrict__ g_w0,
    float* __restrict__ F1, const float* __restrict__ text,
    float* __restrict__ tn, const float* __restrict__ g_w1,
    const float* __restrict__ g_w2, const float* __restrict__ conv1_w,
    const float* __restrict__ conv2_w, const float* __restrict__ conv3_w,
    const float* __restrict__ h_w0, const float* __restrict__ h_w1,
    const float* __restrict__ h_w2, unsigned short* __restrict__ wth,
    unsigned short* __restrict__ wtl) {
  __shared__ __align__(16) float smem[8208];
  const int tid = threadIdx.x;

  if (blockIdx.x < 16) {
    // ===== FPS: 4 waves, thread-major k = tid*8+j, packed-f32 distances ====
    #pragma clang fp contract(off)
    const int b = blockIdx.x;
    float4* pt4 = (float4*)smem;
    unsigned long long (*redw)[4] = (unsigned long long(*)[4])(smem + 8192);
    const float* base = xyz + (size_t)b * Kk * 3;
    for (int i = tid; i < Kk; i += 256) {
      pt4[i] = make_float4(base[3 * i], base[3 * i + 1], base[3 * i + 2], 0.f);
    }
    if (tid == 0) inds[b * Pp] = 0;
    v2f PX[4], PY[4], PZ[4], DM[4];
    {
      const float* pb = base + tid * 24;
      float4 f0 = *(const float4*)(pb + 0);
      float4 f1 = *(const float4*)(pb + 4);
      float4 f2 = *(const float4*)(pb + 8);
      float4 f3 = *(const float4*)(pb + 12);
      float4 f4 = *(const float4*)(pb + 16);
      float4 f5 = *(const float4*)(pb + 20);
      PX[0] = (v2f){f0.x, f0.w}; PY[0] = (v2f){f0.y, f1.x}; PZ[0] = (v2f){f0.z, f1.y};
      PX[1] = (v2f){f1.z, f2.y}; PY[1] = (v2f){f1.w, f2.z}; PZ[1] = (v2f){f2.x, f2.w};
      PX[2] = (v2f){f3.x, f3.w}; PY[2] = (v2f){f3.y, f4.x}; PZ[2] = (v2f){f3.z, f4.y};
      PX[3] = (v2f){f4.z, f5.y}; PY[3] = (v2f){f4.w, f5.z}; PZ[3] = (v2f){f5.x, f5.w};
      #pragma unroll
      for (int p = 0; p < 4; p++) DM[p] = (v2f){1e10f, 1e10f};
    }
    __syncthreads();
    const int lane = tid & 63, wid = tid >> 6;
    int last = 0;
    for (int it = 1; it < Pp; ++it) {
      float4 L = pt4[last];
      v2f vlx = {L.x, L.x}, vly = {L.y, L.y}, vlz = {L.z, L.z};
      float pf[4];
      int pk_[4];
      #pragma unroll
      for (int p = 0; p < 4; p++) {
        v2f dx = PX[p] - vlx, dy = PY[p] - vly, dz = PZ[p] - vlz;
        v2f d = (dx * dx + dy * dy) + dz * dz;
        v2f m2 = __builtin_elementwise_min(DM[p], d);
        DM[p] = m2;
        bool t = m2.y > m2.x;
        pf[p] = t ? m2.y : m2.x;
        pk_[p] = 2 * p + (t ? 1 : 0);
      }
      bool t01 = pf[1] > pf[0];
      float f01 = t01 ? pf[1] : pf[0];
      int k01 = t01 ? pk_[1] : pk_[0];
      bool t23 = pf[3] > pf[2];
      float f23 = t23 ? pf[3] : pf[2];
      int k23 = t23 ? pk_[3] : pk_[2];
      bool tt = f23 > f01;
      float bf = tt ? f23 : f01;
      int bj = tt ? k23 : k01;
      float g = bf;
      g = fmax_dpp<0xB1>(g);
      g = fmax_dpp<0x4E>(g);
      g = fmax_dpp<0x141>(g);
      g = fmax_dpp<0x140>(g);
      g = fmax_dpp<0x142>(g);
      g = fmax_dpp<0x143>(g);
      float gs = __uint_as_float(
          (unsigned)__builtin_amdgcn_readlane(__float_as_int(g), 63));
      unsigned long long msk = __ballot(bf == gs);
      int src = __builtin_ctzll(msk);
      int kk = (tid << 3) | bj;
      int kwin = __builtin_amdgcn_readlane(kk, src);
      if (lane == 0)
        redw[it & 1][wid] = ((unsigned long long)__float_as_uint(gs) << 32) |
                            (unsigned)(~(unsigned)kwin);
      __syncthreads();
      unsigned long long q0 = redw[it & 1][0], q1 = redw[it & 1][1];
      unsigned long long q2 = redw[it & 1][2], q3 = redw[it & 1][3];
      unsigned long long m0 = q0 > q1 ? q0 : q1;
      unsigned long long m1 = q2 > q3 ? q2 : q3;
      unsigned long long mm = m0 > m1 ? m0 : m1;
      last = (int)(~(unsigned)mm);
      if (tid == 0) inds[b * Pp + it] = last;
    }
  } else if (blockIdx.x == 528) {
    int w = tid >> 6, lane = tid & 63;
    for (int r = w; r < 10; r += 4) {
      const float* rw = text + (size_t)r * 512;
      float v[8];
      float ss = 0.f;
      #pragma unroll
      for (int u = 0; u < 8; u++) { v[u] = rw[lane + 64 * u]; ss += v[u] * v[u]; }
      #pragma unroll
      for (int off = 32; off; off >>= 1) ss += __shfl_xor(ss, off, 64);
      float nrm = sqrtf(ss);
      #pragma unroll
      for (int u = 0; u < 8; u++)
        tn[(size_t)r * 512 + lane + 64 * u] = v[u] / nrm;
    }
  } else if (blockIdx.x >= 529) {
    // ===== weight transpose + RNE bf16 split (parallel, 100 blocks) =======
    int wb = blockIdx.x - 529;
    const float* W;
    int K, N, NS, nblk, pidx;
    unsigned short *dh, *dl;
    if (wb < 4)       { W = g_w1;    K = 128; N = 128; NS = 128; dh = wth + WT_GW1; dl = wtl + WT_GW1; nblk = 4;  pidx = wb; }
    else if (wb < 8)  { W = g_w2;    K = 128; N = 128; NS = 128; dh = wth + WT_GW2; dl = wtl + WT_GW2; nblk = 4;  pidx = wb - 4; }
    else if (wb < 12) { W = conv1_w; K = 128; N = 128; NS = 128; dh = wth + WT_C1;  dl = wtl + WT_C1;  nblk = 4;  pidx = wb - 8; }
    else if (wb < 16) { W = conv2_w; K = 128; N = 128; NS = 128; dh = wth + WT_C2;  dl = wtl + WT_C2;  nblk = 4;  pidx = wb - 12; }
    else if (wb < 32) { W = h_w0;    K = 256; N = 512; NS = 512; dh = wth + WT_H0;  dl = wtl + WT_H0;  nblk = 16; pidx = wb - 16; }
    else if (wb < 64) { W = h_w1;    K = 512; N = 512; NS = 512; dh = wth + WT_H1;  dl = wtl + WT_H1;  nblk = 32; pidx = wb - 32; }
    else if (wb < 96) { W = h_w2;    K = 512; N = 512; NS = 512; dh = wth + WT_H2;  dl = wtl + WT_H2;  nblk = 32; pidx = wb - 64; }
    else              { W = conv3_w; K = 128; N = 384; NS = 325; dh = wth + WT_C3;  dl = wtl + WT_C3;  nblk = 4;  pidx = wb - 96; }
    for (int idx = pidx * 256 + tid; idx < K * N; idx += nblk * 256) {
      int k = idx / N, n = idx - k * N;
      float w = (n < NS) ? W[k * NS + n] : 0.f;
      unsigned short hi = f2bf(w);
      unsigned short lo = f2bf(w - bf2f(hi));
      dh[n * K + k] = hi;
      dl[n * K + k] = lo;
    }
  } else {
    // ===== F1 = feats_kc @ g_w0[3:,:]  (32768 x 256 x 128) ================
    float (*a_t)[68] = (float(*)[68])smem;
    float (*b_t)[128] = (float(*)[128])(smem + 32 * 68);
    const float* W = g_w0 + 3 * 128;
    const int m0 = (blockIdx.x - 16) * 64;
    float acc[4][8];
    #pragma unroll
    for (int i = 0; i < 4; i++)
      #pragma unroll
      for (int j = 0; j < 8; j++) acc[i][j] = 0.f;
    const int ty = tid >> 4, tx = tid & 15;
    const int lr = tid & 63, wv = tid >> 6;
    const int bb = m0 >> 11, k0 = m0 & 2047;
    const float* fb = features + (size_t)bb * (Cc * Kk);
    for (int c0 = 0; c0 < 256; c0 += 32) {
      #pragma unroll
      for (int i = 0; i < 8; i++) {
        int c = c0 + wv + 4 * i;
        a_t[wv + 4 * i][lr] = fb[(size_t)c * Kk + k0 + lr];
      }
      #pragma unroll
      for (int p = 0; p < 4; p++) {
        int cc = p * 8 + (tid >> 5);
        int nl = (tid & 31) * 4;
        *(float4*)&b_t[cc][nl] = *(const float4*)&W[(size_t)(c0 + cc) * 128 + nl];
      }
      __syncthreads();
      #pragma unroll
      for (int kk = 0; kk < 32; kk++) {
        float4 av = *(const float4*)&a_t[kk][ty * 4];
        float4 b0 = *(const float4*)&b_t[kk][tx * 4];
        float4 b1 = *(const float4*)&b_t[kk][tx * 4 + 64];
        float ap[4] = {av.x, av.y, av.z, av.w};
        float bq0[4] = {b0.x, b0.y, b0.z, b0.w};
        float bq1[4] = {b1.x, b1.y, b1.z, b1.w};
        #pragma unroll
        for (int i = 0; i < 4; i++) {
          #pragma unroll
          for (int u = 0; u < 4; u++) {
            acc[i][u] = fmaf(ap[i], bq0[u], acc[i][u]);
            acc[i][4 + u] = fmaf(ap[i], bq1[u], acc[i][4 + u]);
          }
        }
      }
      __syncthreads();
    }
    #pragma unroll
    for (int i = 0; i < 4; i++) {
      size_t mrow = (size_t)(m0 + ty * 4 + i);
      #pragma unroll
      for (int gq = 0; gq < 2; gq++) {
        float4 v4 = make_float4(acc[i][gq * 4], acc[i][gq * 4 + 1],
                                acc[i][gq * 4 + 2], acc[i][gq * 4 + 3]);
        *(float4*)&F1[mrow * 128 + gq * 64 + tx * 4] = v4;
      }
    }
  }
}

// -------- neighbor selection + bn0 stats (gather_l1 stats folded in) --------
__global__ __launch_bounds__(256) void neigh_k(
    const float* __restrict__ xyz, const int* __restrict__ inds,
    const float* __restrict__ F1, const float* __restrict__ g_w0,
    int* __restrict__ idxl, float* __restrict__ gx, float* __restrict__ s0,
    float* __restrict__ q0) {
  __shared__ float rs[128], rq[128];
  const int tid = threadIdx.x;
  if (tid < 128) { rs[tid] = 0.f; rq[tid] = 0.f; }
  __syncthreads();
  int widx = blockIdx.x * 4 + (tid >> 6);
  int lane = tid & 63;
  int b = widx >> 9;
  int q = inds[widx];
  const float* base = xyz + (size_t)b * Kk * 3;
  float qx = base[3 * q], qy = base[3 * q + 1], qz = base[3 * q + 2];
  int cnt = 0;
  int myk = 0;
  for (int ch = 0; ch < 32 && cnt < Ss; ch++) {
    int k = ch * 64 + lane;
    float dx = base[3 * k] - qx;
    float dy = base[3 * k + 1] - qy;
    float dz = base[3 * k + 2] - qz;
    float d2 = __fadd_rn(__fadd_rn(__fmul_rn(dx, dx), __fmul_rn(dy, dy)),
                         __fmul_rn(dz, dz));
    unsigned long long m = __ballot(d2 < 0.09f);
    while (m && cnt < Ss) {
      int t = __builtin_ctzll(m);
      if (lane == cnt) myk = ch * 64 + t;
      cnt++;
      m &= m - 1;
    }
  }
  int first = __shfl(myk, 0, 64);
  int kksel = 0;
  float g0r = 0.f, g1r = 0.f, g2r = 0.f;
  if (lane < Ss) {
    int kk = (lane < cnt) ? myk : first;
    kksel = kk;
    g0r = (base[3 * kk] - qx) / 0.3f;
    g1r = (base[3 * kk + 1] - qy) / 0.3f;
    g2r = (base[3 * kk + 2] - qz) / 0.3f;
    size_t o = (size_t)widx * Ss + lane;
    idxl[o] = kk;
    gx[o * 3 + 0] = g0r;
    gx[o * 3 + 1] = g1r;
    gx[o * 3 + 2] = g2r;
  }
  // ---- bn0 stats over the 16 gathered rows (cols: lane and lane+64) ----
  const float* f1b = F1 + (size_t)(b << 11) * 128;
  float wa0 = g_w0[lane], wa1 = g_w0[128 + lane], wa2 = g_w0[256 + lane];
  float wb0 = g_w0[64 + lane], wb1 = g_w0[192 + lane], wb2 = g_w0[320 + lane];
  float sa = 0.f, qa = 0.f, sb = 0.f, qb = 0.f;
  #pragma unroll
  for (int s = 0; s < Ss; s++) {
    int bidx = __shfl(kksel, s, 64);
    float gg0 = __shfl(g0r, s, 64);
    float gg1 = __shfl(g1r, s, 64);
    float gg2 = __shfl(g2r, s, 64);
    const float* fr = f1b + (size_t)bidx * 128;
    float va = fr[lane] + gg0 * wa0 + gg1 * wa1 + gg2 * wa2;
    float vb = fr[64 + lane] + gg0 * wb0 + gg1 * wb1 + gg2 * wb2;
    sa += va; qa += va * va;
    sb += vb; qb += vb * vb;
  }
  atomicAdd(&rs[lane], sa);
  atomicAdd(&rq[lane], qa);
  atomicAdd(&rs[64 + lane], sb);
  atomicAdd(&rq[64 + lane], qb);
  __syncthreads();
  if (tid < 128) {
    atomicAdd(&s0[tid], rs[tid]);
    atomicAdd(&q0[tid], rq[tid]);
  }
}

// ------- split-bf16 MFMA GEMM: out = act_in(A) @ (Wh+Wl)^T (+bias) ---------
// GATHER: A[row] = F1[gidx[row]] + gx(row).w_xyz  (inline gather, f32 src)
// ABF16 : A stored bf16. OBF16: store bf16.
// OMAX  : emit per-16-row-group max. WCLIP: split cols -> net / clipf.
template <int KD, bool INBN, bool HASBIAS, bool OSUM, bool OMAX, bool WCLIP,
          bool ABF16, bool GATHER, bool OBF16>
__global__ __launch_bounds__(256, 2) void gemm_mfma(
    const void* __restrict__ A, const unsigned short* __restrict__ Wh,
    const unsigned short* __restrict__ Wl, const float* __restrict__ bias,
    const float* __restrict__ isum, const float* __restrict__ isq,
    float inv_cnt, const float* __restrict__ gamma,
    const float* __restrict__ beta, void* __restrict__ outp, int N, int nout,
    float* __restrict__ clipf, float* __restrict__ osum,
    float* __restrict__ osq, const int* __restrict__ idxl,
    const float* __restrict__ gxv, const float* __restrict__ w0raw) {
  __shared__ float sc[INBN ? KD : 1];
  __shared__ float sh[INBN ? KD : 1];
  __shared__ float red_s[OSUM ? 128 : 1];
  __shared__ float red_q[OSUM ? 128 : 1];
  const int tid = threadIdx.x;
  if (INBN) {
    for (int c = tid; c < KD; c += 256) {
      float mean = isum[c] * inv_cnt;
      float var = isq[c] * inv_cnt - mean * mean;
      float is_ = rsqrtf(var + 1e-5f);
      float scl = gamma[c] * is_;
      sc[c] = scl;
      sh[c] = beta[c] - mean * scl;
    }
  }
  if (OSUM && tid < 128) { red_s[tid] = 0.f; red_q[tid] = 0.f; }
  __syncthreads();
  const int wave = tid >> 6, lane = tid & 63;
  const int wm = wave >> 1, wn = wave & 1;
  const int r = lane & 15, g = lane >> 4;
  const size_t m0 = (size_t)blockIdx.x * 128 + wm * 64;
  const int n0 = blockIdx.y * 128 + wn * 64;

  const float* Af = (const float*)A;
  const unsigned short* Ab = (const unsigned short*)A;

  size_t gi[4];
  float gx0[4], gx1[4], gx2[4];
  if (GATHER) {
    #pragma unroll
    for (int mf = 0; mf < 4; mf++) {
      int row = (int)m0 + mf * 16 + r;
      gi[mf] = ((size_t)((row >> 13) << 11) + idxl[row]) * 128;
      gx0[mf] = gxv[3 * (size_t)row];
      gx1[mf] = gxv[3 * (size_t)row + 1];
      gx2[mf] = gxv[3 * (size_t)row + 2];
    }
  }

  f32x4 acc[4][4] = {};
  for (int ks = 0; ks < KD / 32; ks++) {
    const int kb = ks * 32 + g * 8;
    bf16x8 bh[4], bl[4];
    #pragma unroll
    for (int nf = 0; nf < 4; nf++) {
      bh[nf] = *(const bf16x8*)&Wh[(size_t)(n0 + nf * 16 + r) * KD + kb];
      bl[nf] = *(const bf16x8*)&Wl[(size_t)(n0 + nf * 16 + r) * KD + kb];
    }
    float s8[8], h8[8];
    if (INBN) {
      #pragma unroll
      for (int j = 0; j < 8; j++) { s8[j] = sc[kb + j]; h8[j] = sh[kb + j]; }
    }
    float wxr[8], wyr[8], wzr[8];
    if (GATHER) {
      float4 a0 = *(const float4*)&w0raw[kb];
      float4 a1 = *(const float4*)&w0raw[kb + 4];
      float4 b0 = *(const float4*)&w0raw[128 + kb];
      float4 b1 = *(const float4*)&w0raw[128 + kb + 4];
      float4 c0 = *(const float4*)&w0raw[256 + kb];
      float4 c1 = *(const float4*)&w0raw[256 + kb + 4];
      wxr[0]=a0.x; wxr[1]=a0.y; wxr[2]=a0.z; wxr[3]=a0.w;
      wxr[4]=a1.x; wxr[5]=a1.y; wxr[6]=a1.z; wxr[7]=a1.w;
      wyr[0]=b0.x; wyr[1]=b0.y; wyr[2]=b0.z; wyr[3]=b0.w;
      wyr[4]=b1.x; wyr[5]=b1.y; wyr[6]=b1.z; wyr[7]=b1.w;
      wzr[0]=c0.x; wzr[1]=c0.y; wzr[2]=c0.z; wzr[3]=c0.w;
      wzr[4]=c1.x; wzr[5]=c1.y; wzr[6]=c1.z; wzr[7]=c1.w;
    }
    #pragma unroll
    for (int mf = 0; mf < 4; mf++) {
      float xv[8];
      if (GATHER) {
        const float* fp = Af + gi[mf] + kb;
        float4 x0 = *(const float4*)fp;
        float4 x1 = *(const float4*)(fp + 4);
        xv[0]=x0.x; xv[1]=x0.y; xv[2]=x0.z; xv[3]=x0.w;
        xv[4]=x1.x; xv[5]=x1.y; xv[6]=x1.z; xv[7]=x1.w;
        #pragma unroll
        for (int j = 0; j < 8; j++)
          xv[j] += gx0[mf] * wxr[j] + gx1[mf] * wyr[j] + gx2[mf] * wzr[j];
      } else if (ABF16) {
        bf16x8 rawv = *(const bf16x8*)&Ab[(m0 + mf * 16 + r) * KD + kb];
        #pragma unroll
        for (int j = 0; j < 8; j++) xv[j] = bf2f((unsigned short)rawv[j]);
      } else {
        const float* ap = Af + (m0 + mf * 16 + r) * KD + kb;
        float4 x0 = *(const float4*)ap;
        float4 x1 = *(const float4*)(ap + 4);
        xv[0]=x0.x; xv[1]=x0.y; xv[2]=x0.z; xv[3]=x0.w;
        xv[4]=x1.x; xv[5]=x1.y; xv[6]=x1.z; xv[7]=x1.w;
      }
      bf16x8 ah, al;
      #pragma unroll
      for (int j = 0; j < 8; j++) {
        float x = xv[j];
        if (INBN) x = fmaxf(fmaf(x, s8[j], h8[j]), 0.f);
        short hh, ll;
        split2(x, hh, ll);
        ah[j] = hh;
        al[j] = ll;
      }
      #pragma unroll
      for (int nf = 0; nf < 4; nf++) {
        acc[mf][nf] = __builtin_amdgcn_mfma_f32_16x16x32_bf16(
            ah, bh[nf], acc[mf][nf], 0, 0, 0);
        acc[mf][nf] = __builtin_amdgcn_mfma_f32_16x16x32_bf16(
            al, bh[nf], acc[mf][nf], 0, 0, 0);
        acc[mf][nf] = __builtin_amdgcn_mfma_f32_16x16x32_bf16(
            ah, bl[nf], acc[mf][nf], 0, 0, 0);
      }
    }
  }
  float bv[4];
  if (HASBIAS) {
    #pragma unroll
    for (int nf = 0; nf < 4; nf++) {
      int col = n0 + nf * 16 + r;
      bv[nf] = (!WCLIP || col < nout) ? bias[col] : 0.f;
    }
  }
  float ps[4] = {0.f, 0.f, 0.f, 0.f}, pq[4] = {0.f, 0.f, 0.f, 0.f};
  #pragma unroll
  for (int mf = 0; mf < 4; mf++) {
    float mx[4];
    #pragma unroll
    for (int nf = 0; nf < 4; nf++) {
      float vmax = -1e30f;
      #pragma unroll
      for (int j = 0; j < 4; j++) {
        float v = acc[mf][nf][j];
        if (HASBIAS) v += bv[nf];
        size_t row = m0 + mf * 16 + g * 4 + j;
        int col = n0 + nf * 16 + r;
        if (OSUM) { ps[nf] += v; pq[nf] += v * v; }
        if (OMAX) {
          vmax = fmaxf(vmax, v);
        } else if (WCLIP) {
          if (col < 69) ((float*)outp)[row * 69 + col] = v;
          else if (col < nout) clipf[row * 256 + (col - 69)] = v;
        } else if (OBF16) {
          ((unsigned short*)outp)[row * N + col] = f2bf(v);
        } else {
          ((float*)outp)[row * N + col] = v;
        }
      }
      mx[nf] = vmax;
    }
    if (OMAX) {
      #pragma unroll
      for (int nf = 0; nf < 4; nf++) {
        float m = mx[nf];
        m = fmaxf(m, __shfl_xor(m, 16, 64));
        m = fmaxf(m, __shfl_xor(m, 32, 64));
        if (g == 0) {
          size_t bq = (m0 >> 4) + mf;
          ((float*)outp)[bq * 128 + n0 + nf * 16 + r] = m;
        }
      }
    }
  }
  if (OSUM) {
    #pragma unroll
    for (int nf = 0; nf < 4; nf++) {
      #pragma unroll
      for (int off = 16; off < 64; off <<= 1) {
        ps[nf] += __shfl_xor(ps[nf], off, 64);
        pq[nf] += __shfl_xor(pq[nf], off, 64);
      }
    }
    if (lane < 16) {
      #pragma unroll
      for (int nf = 0; nf < 4; nf++) {
        int lcol = wn * 64 + nf * 16 + r;
        atomicAdd(&red_s[lcol], ps[nf]);
        atomicAdd(&red_q[lcol], pq[nf]);
      }
    }
    __syncthreads();
    if (tid < 128) {
      atomicAdd(&osum[blockIdx.y * 128 + tid], red_s[tid]);
      atomicAdd(&osq[blockIdx.y * 128 + tid], red_q[tid]);
    }
  }
}

// ---------------- final: q-norm, logits, coalesced transpose-assemble -------
__global__ __launch_bounds__(512) void final2(const float* __restrict__ net,
                                              const float* __restrict__ qbuf,
                                              const float* __restrict__ tn,
                                              float* __restrict__ out) {
  __shared__ float tile[79][65];
  const int blk = blockIdx.x;
  const int tid = threadIdx.x;
  const int r = tid >> 3, oct = tid & 7;
  const int row = blk * 64 + r;
  const int b = (blk * 64) >> 9, p0 = (blk * 64) & 511;

  const float* qr = qbuf + (size_t)row * 512 + oct * 64;
  float4 q4[16];
  #pragma unroll
  for (int i = 0; i < 16; i++) q4[i] = *(const float4*)(qr + 4 * i);
  float ss = 0.f;
  float dot[10];
  #pragma unroll
  for (int t = 0; t < 10; t++) dot[t] = 0.f;
  #pragma unroll
  for (int i = 0; i < 16; i++) {
    float4 a = q4[i];
    ss += a.x * a.x + a.y * a.y + a.z * a.z + a.w * a.w;
    #pragma unroll
    for (int t = 0; t < 10; t++) {
      float4 b4 = *(const float4*)(tn + (size_t)t * 512 + oct * 64 + i * 4);
      dot[t] += a.x * b4.x + a.y * b4.y + a.z * b4.z + a.w * b4.w;
    }
  }
  #pragma unroll
  for (int off = 1; off < 8; off <<= 1) {
    ss += __shfl_xor(ss, off, 8);
    #pragma unroll
    for (int t = 0; t < 10; t++) dot[t] += __shfl_xor(dot[t], off, 8);
  }
  if (oct == 0) {
    float inv = rsqrtf(ss) * (1.f / 0.07f);
    #pragma unroll
    for (int t = 0; t < 10; t++) tile[69 + t][r] = dot[t] * inv;
  }
  for (int idx = tid; idx < 64 * 69; idx += 512) {
    int r2 = idx / 69, ch = idx - 69 * r2;
    tile[ch][r2] = net[(size_t)(blk * 64 + r2) * 69 + ch];
  }
  __syncthreads();
  for (int idx = tid; idx < 79 * 64; idx += 512) {
    int ch = idx >> 6, rr = idx & 63;
    out[((size_t)b * 79 + ch) * 512 + p0 + rr] = tile[ch][rr];
  }
}

extern "C" void kernel_launch(void* const* d_in, const int* in_sizes, int n_in,
                              void* d_out, int out_size, void* d_ws,
                              size_t ws_size, hipStream_t stream) {
  const float* xyz = (const float*)d_in[0];
  const float* features = (const float*)d_in[1];
  const float* text = (const float*)d_in[2];
  const float* g_w0 = (const float*)d_in[3];
  const float* g_w1 = (const float*)d_in[4];
  const float* g_w2 = (const float*)d_in[5];
  const float* g_gam0 = (const float*)d_in[6];
  const float* g_bet0 = (const float*)d_in[7];
  const float* g_gam1 = (const float*)d_in[8];
  const float* g_bet1 = (const float*)d_in[9];
  const float* g_gam2 = (const float*)d_in[10];
  const float* g_bet2 = (const float*)d_in[11];
  const float* conv1_w = (const float*)d_in[12];
  const float* conv1_b = (const float*)d_in[13];
  const float* bn1_g = (const float*)d_in[14];
  const float* bn1_b = (const float*)d_in[15];
  const float* conv2_w = (const float*)d_in[16];
  const float* conv2_b = (const float*)d_in[17];
  const float* bn2_g = (const float*)d_in[18];
  const float* bn2_b = (const float*)d_in[19];
  const float* conv3_w = (const float*)d_in[20];
  const float* conv3_b = (const float*)d_in[21];
  const float* h_w0 = (const float*)d_in[22];
  const float* h_b0 = (const float*)d_in[23];
  const float* h_g0 = (const float*)d_in[24];
  const float* h_be0 = (const float*)d_in[25];
  const float* h_w1 = (const float*)d_in[26];
  const float* h_b1 = (const float*)d_in[27];
  const float* h_g1 = (const float*)d_in[28];
  const float* h_be1 = (const float*)d_in[29];
  const float* h_w2 = (const float*)d_in[30];
  const float* h_b2 = (const float*)d_in[31];
  float* out = (float*)d_out;
  char* ws = (char*)d_ws;

  float* tn = (float*)(ws + OFF_TNORM);
  float* sums = (float*)(ws + OFF_SUMS);
  int* inds = (int*)(ws + OFF_INDS);
  int* idxl = (int*)(ws + OFF_IDXL);
  float* gx = (float*)(ws + OFF_GX);
  float* F1 = (float*)(ws + OFF_F1);
  unsigned short* L2OUT = (unsigned short*)(ws + OFF_BIGA);
  float* QF = (float*)(ws + OFF_BIGA);
  float* FEAT = (float*)(ws + OFF_BIGB);
  float* C1F = (float*)(ws + OFF_BIGB + 4194304);
  float* C2F = (float*)(ws + OFF_BIGB + 8388608);
  float* CLIPF = (float*)(ws + OFF_BIGB + 12582912);
  float* H0F = (float*)(ws + OFF_BIGB + 20971520);
  float* H1F = (float*)(ws + OFF_BIGB + 37748736);
  float* net = (float*)(ws + OFF_NET);
  unsigned short* WTH = (unsigned short*)(ws + OFF_WTH);
  unsigned short* WTL = (unsigned short*)(ws + OFF_WTL);

  hipMemsetAsync(sums, 0, 16384, stream);
  fused_pre<<<629, 256, 0, stream>>>(xyz, inds, features, g_w0, F1, text, tn,
                                     g_w1, g_w2, conv1_w, conv2_w, conv3_w,
                                     h_w0, h_w1, h_w2, WTH, WTL);
  // neighbor selection + bn0 stats (gather_l1 eliminated)
  neigh_k<<<2048, 256, 0, stream>>>(xyz, inds, F1, g_w0, idxl, gx,
                                    sums + SB0S, sums + SB0Q);
  // L2 = relu(bn0(gather(F1)+gx.w)) @ g_w1  (inline gather, bf16 out)
  gemm_mfma<128, true, false, true, false, false, false, true, true>
      <<<dim3(1024, 1), 256, 0, stream>>>(
          F1, WTH + WT_GW1, WTL + WT_GW1, nullptr, sums + SB0S, sums + SB0Q,
          1.f / 131072.f, g_gam0, g_bet0, L2OUT, 128, 128, nullptr,
          sums + SB1S, sums + SB1Q, idxl, gx, g_w0);
  // L3 = relu(bn1(L2)) @ g_w2, fused raw max over S=16 -> FEAT (+bn2 stats)
  gemm_mfma<128, true, false, true, true, false, true, false, false>
      <<<dim3(1024, 1), 256, 0, stream>>>(
          L2OUT, WTH + WT_GW2, WTL + WT_GW2, nullptr, sums + SB1S,
          sums + SB1Q, 1.f / 131072.f, g_gam1, g_bet1, FEAT, 128, 128,
          nullptr, sums + SB2S, sums + SB2Q, nullptr, nullptr, nullptr);
  // c1 = relu(bn2(feat)) @ conv1_w + b
  gemm_mfma<128, true, true, true, false, false, false, false, false>
      <<<dim3(64, 1), 256, 0, stream>>>(
          FEAT, WTH + WT_C1, WTL + WT_C1, conv1_b, sums + SB2S, sums + SB2Q,
          1.f / 131072.f, g_gam2, g_bet2, C1F, 128, 128, nullptr, sums + SC1S,
          sums + SC1Q, nullptr, nullptr, nullptr);
  // c2 = relu(bn(c1)) @ conv2_w + b
  gemm_mfma<128, true, true, true, false, false, false, false, false>
      <<<dim3(64, 1), 256, 0, stream>>>(
          C1F, WTH + WT_C2, WTL + WT_C2, conv2_b, sums + SC1S, sums + SC1Q,
          1.f / 8192.f, bn1_g, bn1_b, C2F, 128, 128, nullptr, sums + SC2S,
          sums + SC2Q, nullptr, nullptr, nullptr);
  // net/clip = relu(bn(c2)) @ conv3_w + b  (N padded 384, nout=325)
  gemm_mfma<128, true, true, false, false, true, false, false, false>
      <<<dim3(64, 3), 256, 0, stream>>>(
          C2F, WTH + WT_C3, WTL + WT_C3, conv3_b, sums + SC2S, sums + SC2Q,
          1.f / 8192.f, bn2_g, bn2_b, net, 384, 325, CLIPF, nullptr, nullptr,
          nullptr, nullptr, nullptr);
  // h0 = clip_in @ h_w0 + b
  gemm_mfma<256, false, true, true, false, false, false, false, false>
      <<<dim3(64, 4), 256, 0, stream>>>(
          CLIPF, WTH + WT_H0, WTL + WT_H0, h_b0, nullptr, nullptr, 0.f,
          nullptr, nullptr, H0F, 512, 512, nullptr, sums + SH0S, sums + SH0Q,
          nullptr, nullptr, nullptr);
  // h1 = relu(bn(h0)) @ h_w1 + b
  gemm_mfma<512, true, true, true, false, false, false, false, false>
      <<<dim3(64, 4), 256, 0, stream>>>(
          H0F, WTH + WT_H1, WTL + WT_H1, h_b1, sums + SH0S, sums + SH0Q,
          1.f / 8192.f, h_g0, h_be0, H1F, 512, 512, nullptr, sums + SH1S,
          sums + SH1Q, nullptr, nullptr, nullptr);
  // q = relu(bn(h1)) @ h_w2 + b
  gemm_mfma<512, true, true, false, false, false, false, false, false>
      <<<dim3(64, 4), 256, 0, stream>>>(
          H1F, WTH + WT_H2, WTL + WT_H2, h_b2, sums + SH1S, sums + SH1Q,
          1.f / 8192.f, h_g1, h_be1, QF, 512, 512, nullptr, nullptr, nullptr,
          nullptr, nullptr, nullptr);
  final2<<<128, 512, 0, stream>>>(net, QF, tn, out);
}